// Round 17
// baseline (494.162 us; speedup 1.0000x reference)
//
#include <hip/hip_runtime.h>
#include <stdint.h>

// Problem constants
#define B_SZ 4
#define T_SEQ 2048
#define H_DIM 2048
#define NH_ 16
#define HD_ 128
#define MTOK (B_SZ * T_SEQ) // 8192

typedef __attribute__((ext_vector_type(8))) short bf16x8;
typedef __attribute__((ext_vector_type(4))) float f32x4;
typedef __attribute__((ext_vector_type(4))) unsigned short u16x4;

__device__ __forceinline__ unsigned short f2b(float f) {
  union { float f; uint32_t u; } x; x.f = f;
  uint32_t r = x.u + 0x7FFFu + ((x.u >> 16) & 1u); // RNE
  return (unsigned short)(r >> 16);
}

__device__ __forceinline__ void gload16(const void* g, void* l) {
  // width-16 global->LDS DMA; LDS dest is wave-uniform base, HW scatters lane*16
  __builtin_amdgcn_global_load_lds((const __attribute__((address_space(1))) void*)g,
                                   (__attribute__((address_space(3))) void*)l, 16, 0, 0);
}

// ---------------- f32 -> bf16 conversion ----------------
__global__ void cvt_bf16_k(const float* __restrict__ in, unsigned short* __restrict__ out, int n4) {
  for (int i = blockIdx.x * blockDim.x + threadIdx.x; i < n4; i += gridDim.x * blockDim.x) {
    float4 v = ((const float4*)in)[i];
    u16x4 o;
    o[0] = f2b(v.x); o[1] = f2b(v.y); o[2] = f2b(v.z); o[3] = f2b(v.w);
    ((u16x4*)out)[i] = o;
  }
}

// 4 weight matrices (each 1M float4 groups) in one launch; buffer = idx >> 20.
__global__ void cvt4_bf16_k(const float* __restrict__ s0, const float* __restrict__ s1,
                            const float* __restrict__ s2, const float* __restrict__ s3,
                            unsigned short* __restrict__ d0, unsigned short* __restrict__ d1,
                            unsigned short* __restrict__ d2, unsigned short* __restrict__ d3) {
  const int n4each = (H_DIM * H_DIM) / 4; // 1M
  for (int i = blockIdx.x * blockDim.x + threadIdx.x; i < 4 * n4each; i += gridDim.x * blockDim.x) {
    int sel = i >> 20, j = i & (n4each - 1);
    const float* src = sel == 0 ? s0 : sel == 1 ? s1 : sel == 2 ? s2 : s3;
    unsigned short* dst = sel == 0 ? d0 : sel == 1 ? d1 : sel == 2 ? d2 : d3;
    float4 v = ((const float4*)src)[j];
    u16x4 o;
    o[0] = f2b(v.x); o[1] = f2b(v.y); o[2] = f2b(v.z); o[3] = f2b(v.w);
    ((u16x4*)dst)[j] = o;
  }
}

// ---------------- GEMM 256x256 tile, BK=64, 8 waves (r12-verified loop) ----------
// C[m][n] = (sum_k A[m][k] * W[n][k] + bias[n]) * oscale(MODE0 only)
// MODE 0: bf16 out, scatter to [B, NH, T, HD]   (Q pre-scaled) — LDS-coalesced epi
// MODE 3: bf16 out, [B, NH, T, HD] + intra-64 row permutation (K) — LDS-coalesced epi
// MODE 1: bf16 out, scatter to [B, NH, HD, T]   (V transposed, linear kv)
// MODE 2: f32 out, row-major [M, N]             (final projection)
template <int MODE>
__global__ __launch_bounds__(512, 2) void gemm256_k(const unsigned short* __restrict__ A,
                                                    const unsigned short* __restrict__ W,
                                                    const float* __restrict__ bias,
                                                    void* __restrict__ outp,
                                                    float oscale) {
  constexpr int K = H_DIM;   // 2048
  constexpr int NT = K / 64; // 32 K-tiles
  __shared__ __align__(16) unsigned short Al[2][256 * 64];
  __shared__ __align__(16) unsigned short Bl[2][256 * 64];

  const int tid = threadIdx.x;
  const int w = tid >> 6, l = tid & 63;
  const int g = l >> 4, ln = l & 15;
  const int wr = w >> 2, wc = w & 3;

  const int bid = blockIdx.x + gridDim.x * blockIdx.y;
  const int fid = ((bid & 7) << 5) | (bid >> 3);
  const int col0 = (fid & 7) * 256;
  const int row0 = (fid >> 3) * 256;

  const char* Ag = (const char*)A;
  const char* Wg = (const char*)W;

  const int srow = l >> 3;
  const int sbyte = ((l & 7) * 16) ^ (srow << 4);

#define ST_A(t2, b2, c)                                                                 \
  gload16(Ag + (((size_t)(row0 + (c) * 8 + srow)) * K + (t2) * 64) * 2 + sbyte,         \
          (char*)&Al[b2][0] + (c) * 1024)
#define ST_B(t2, b2, c)                                                                 \
  gload16(Wg + (((size_t)(col0 + (c) * 8 + srow)) * K + (t2) * 64) * 2 + sbyte,         \
          (char*)&Bl[b2][0] + (c) * 1024)
#define STAGE_A0(t2, b2) do { ST_A(t2, b2, w);  ST_A(t2, b2, 16 + w); } while (0)
#define STAGE_A1(t2, b2) do { ST_A(t2, b2, 8 + w); ST_A(t2, b2, 24 + w); } while (0)
#define STAGE_B0(t2, b2) do { int c_ = (w >> 2) * 8 + (w & 3); ST_B(t2, b2, c_); ST_B(t2, b2, 16 + c_); } while (0)
#define STAGE_B1(t2, b2) do { int c_ = (w >> 2) * 8 + 4 + (w & 3); ST_B(t2, b2, c_); ST_B(t2, b2, 16 + c_); } while (0)

  f32x4 acc[8][4] = {};
  bf16x8 aF[4][2];
  bf16x8 bF[2][2][2];

#define READ_A(mh)                                                                      \
  _Pragma("unroll") for (int mf = 0; mf < 4; ++mf)                                      \
  _Pragma("unroll") for (int ks = 0; ks < 2; ++ks) {                                    \
    int row_ = wr * 128 + (mh) * 64 + mf * 16 + ln;                                     \
    aF[mf][ks] = *(const bf16x8*)((const char*)Ab + row_ * 128 +                        \
                                  ((ks * 64 + g * 16) ^ ((ln & 7) << 4)));              \
  }
#define READ_B(nh)                                                                      \
  _Pragma("unroll") for (int nf = 0; nf < 2; ++nf)                                      \
  _Pragma("unroll") for (int ks = 0; ks < 2; ++ks) {                                    \
    int row_ = wc * 64 + (nh) * 32 + nf * 16 + ln;                                      \
    bF[nh][nf][ks] = *(const bf16x8*)((const char*)Bb + row_ * 128 +                    \
                                      ((ks * 64 + g * 16) ^ ((ln & 7) << 4)));          \
  }
#define MFMA_PHASE(mh, nh)                                                              \
  do {                                                                                  \
    __builtin_amdgcn_s_setprio(1);                                                      \
    _Pragma("unroll") for (int mf = 0; mf < 4; ++mf)                                    \
    _Pragma("unroll") for (int nf = 0; nf < 2; ++nf)                                    \
    _Pragma("unroll") for (int ks = 0; ks < 2; ++ks)                                    \
      acc[(mh) * 4 + mf][(nh) * 2 + nf] = __builtin_amdgcn_mfma_f32_16x16x32_bf16(      \
          aF[mf][ks], bF[nh][nf][ks], acc[(mh) * 4 + mf][(nh) * 2 + nf], 0, 0, 0);      \
    __builtin_amdgcn_s_setprio(0);                                                      \
  } while (0)
#define WAITL()  asm volatile("s_waitcnt lgkmcnt(0)" ::: "memory")
#define BARRIER() asm volatile("s_barrier" ::: "memory")

  STAGE_A0(0, 0); STAGE_B0(0, 0); STAGE_B1(0, 0); STAGE_A1(0, 0);
  STAGE_A0(1, 1); STAGE_B0(1, 1); STAGE_B1(1, 1); STAGE_A1(1, 1);
  asm volatile("s_waitcnt vmcnt(8)" ::: "memory");
  BARRIER();

#pragma unroll 1
  for (int t = 0; t < NT; ++t) {
    const int buf = t & 1;
    const unsigned short* Ab = &Al[buf][0];
    const unsigned short* Bb = &Bl[buf][0];
    READ_A(0); READ_B(0);
    if (t >= 1 && t + 1 < NT) STAGE_A1(t + 1, (t + 1) & 1);
    BARRIER();
    MFMA_PHASE(0, 0);
    BARRIER();
    READ_B(1);
    if (t + 2 < NT) STAGE_A0(t + 2, buf);
    BARRIER();
    MFMA_PHASE(0, 1);
    BARRIER();
    READ_A(1);
    if (t + 2 < NT) STAGE_B0(t + 2, buf);
    BARRIER();
    MFMA_PHASE(1, 0);
    BARRIER();
    if (t + 2 < NT) {
      STAGE_B1(t + 2, buf);
      asm volatile("s_waitcnt vmcnt(6)" ::: "memory");
    } else {
      asm volatile("s_waitcnt vmcnt(0)" ::: "memory");
    }
    BARRIER();
    MFMA_PHASE(1, 1);
    BARRIER();
  }

  // ---- epilogue ----
  if constexpr (MODE == 0 || MODE == 3) {
    // LDS-transposed coalesced epilogue: 4 chunks of 64 C-rows. Owner waves
    // (wr == ch>>1) deposit f2b(acc+bias) into a stride-260 bf16 scratch
    // (bank = 8g+2r+8ni+(ln>>1): all 32 banks, 2 lanes each -> conflict-free),
    // then all 512 threads store 8 passes of 64-lane x 8B runs (256B/head, fully
    // coalesced). MODE 3 applies the intra-64 kv row permutation on t at store.
    unsigned short* out = (unsigned short*)outp;
    unsigned short* lbuf = &Al[0][0]; // 64 x 260 bf16 = 33.3 KB, fits Al
    const int rw = tid >> 6, l8 = tid & 63;
#pragma unroll 1
    for (int ch = 0; ch < 4; ++ch) {
      if (wr == (ch >> 1)) {
        const int mh = ch & 1;
#pragma unroll
        for (int mi = 0; mi < 4; ++mi) {
#pragma unroll
          for (int ni = 0; ni < 4; ++ni) {
            int n = col0 + wc * 64 + ni * 16 + ln;
            float bv = bias[n];
#pragma unroll
            for (int r = 0; r < 4; ++r)
              lbuf[(mi * 16 + 4 * g + r) * 260 + wc * 64 + ni * 16 + ln] =
                  f2b((acc[mh * 4 + mi][ni][r] + bv) * oscale);
          }
        }
      }
      WAITL();
      BARRIER();
#pragma unroll
      for (int p = 0; p < 8; ++p) {
        int row = p * 8 + rw;                         // 0..63
        int m = row0 + (ch >> 1) * 128 + (ch & 1) * 64 + row;
        int b = m >> 11, t = m & 2047;
        if constexpr (MODE == 3) {
          int tl = t & 63;
          t = (t & ~63) | ((tl >> 5) * 32 + ((tl >> 2) & 1) * 16 + ((tl >> 3) & 3) * 4 + (tl & 3));
        }
        int nn = l8 * 4;                              // col (bf16 units) 0..252
        int h = (col0 + nn) >> 7, d = nn & 127;
        *(uint2*)&out[(((size_t)(b * NH_ + h)) * T_SEQ + t) * HD_ + d] =
            *(const uint2*)&lbuf[row * 260 + nn];
      }
      BARRIER();
    }
  } else {
#pragma unroll
    for (int mi = 0; mi < 8; ++mi) {
#pragma unroll
      for (int ni = 0; ni < 4; ++ni) {
        int n = col0 + wc * 64 + ni * 16 + ln;
        float bv = bias[n];
        if constexpr (MODE == 2) {
          float* out = (float*)outp;
#pragma unroll
          for (int r = 0; r < 4; ++r) {
            int m = row0 + wr * 128 + mi * 16 + 4 * g + r;
            out[(size_t)m * H_DIM + n] = acc[mi][ni][r] + bv;
          }
        } else { // MODE 1: V transposed [B, NH, HD, T], linear kv columns
          unsigned short* out = (unsigned short*)outp;
          int h = n >> 7, d = n & 127;
          int m0 = row0 + wr * 128 + mi * 16 + 4 * g;
          int b = m0 >> 11, t0 = m0 & 2047;
          u16x4 pk;
#pragma unroll
          for (int r = 0; r < 4; ++r) pk[r] = f2b(acc[mi][ni][r] + bv);
          *(u16x4*)&out[(((size_t)(b * NH_ + h)) * HD_ + d) * T_SEQ + t0] = pk;
        }
      }
    }
  }
#undef ST_A
#undef ST_B
#undef STAGE_A0
#undef STAGE_A1
#undef STAGE_B0
#undef STAGE_B1
#undef READ_A
#undef READ_B
#undef MFMA_PHASE
#undef WAITL
#undef BARRIER
}

// ---------------- causal flash attention (r16-verified, ~104 us) ----------------
// QBLK=128 (4 waves), 512 blocks, serial q-tile pair (15-pr, pr) -> 34 iters each;
// 2 blocks/CU. K rows pre-permuted (MODE 3) -> shuffle-free P routing; in-reg P.
__global__ __launch_bounds__(256, 2) void attn128_k(const unsigned short* __restrict__ Q,
                                                    const unsigned short* __restrict__ Kg,
                                                    const unsigned short* __restrict__ Vt,
                                                    unsigned short* __restrict__ ctx) {
  __shared__ __align__(16) unsigned short Kl[2][64 * 128]; // [kv-slot][k] swizzled rows (256B)
  __shared__ __align__(16) unsigned short Vl[2][128 * 64]; // [d][kv] swizzled rows (128B)

  const int tid = threadIdx.x;
  const int w = tid >> 6, l = tid & 63;   // w: 0..3
  const int g = l >> 4, ln = l & 15;

  // XCD grouping: 512 blocks -> 64 consecutive per XCD; each bh's 8 blocks on one XCD
  const int flat = ((blockIdx.x & 7) << 6) | (blockIdx.x >> 3);
  const int bh = flat >> 3;  // 0..63
  const int pr = flat & 7;   // 0..7 -> q-tile pair (15-pr, pr)

  const char* kbase = (const char*)(Kg + (size_t)bh * T_SEQ * HD_);
  const char* vbase = (const char*)(Vt + (size_t)bh * HD_ * T_SEQ);
  const int b = bh >> 4, h = bh & 15;

#define STAGE_KV(bufi, ktile) do {                                                    \
    int kv0_ = (ktile) * 64;                                                          \
    _Pragma("unroll")                                                                 \
    for (int i_ = 0; i_ < 4; ++i_) {                                                  \
      int c_ = w * 4 + i_;                                                            \
      int kvr_ = c_ * 4 + g;                                                          \
      gload16(kbase + ((size_t)(kv0_ + kvr_) * HD_) * 2 + ((ln * 16) ^ ((kvr_ & 7) << 4)), \
              (char*)&Kl[bufi][0] + c_ * 1024);                                       \
      int d_ = c_ * 8 + (l >> 3);                                                     \
      gload16(vbase + ((size_t)d_ * T_SEQ + kv0_) * 2 + (((l & 7) * 16) ^ ((d_ & 7) << 4)), \
              (char*)&Vl[bufi][0] + c_ * 1024);                                       \
    } } while (0)

#pragma unroll 1
  for (int half = 0; half < 2; ++half) {
    const int qt = half ? pr : (15 - pr); // heavy 128-row tile first
    const int q0 = qt << 7;
    const int qw = q0 + w * 32;           // wave's first q row

    bf16x8 bq[2][4];
#pragma unroll
    for (int f = 0; f < 2; ++f)
#pragma unroll
      for (int kk = 0; kk < 4; ++kk)
        bq[f][kk] = *(const bf16x8*)(Q + ((size_t)bh * T_SEQ + qw + f * 16 + ln) * HD_ + kk * 32 + g * 8);

    f32x4 acc[2][8] = {};
    float mrun[2] = {-INFINITY, -INFINITY};
    float lrun[2] = {0.f, 0.f};

    const int nt = (qt + 1) * 2;

    STAGE_KV(0, 0);
    __syncthreads();
    int cur = 0;

#pragma unroll 1
    for (int kt = 0; kt < nt; ++kt) {
      if (kt + 1 < nt) STAGE_KV(cur ^ 1, kt + 1); // prefetch overlaps compute
      const int kv0 = kt * 64;
      if (kv0 <= qw + 31) { // causal wave-skip (barriers stay outside)
        const char* kl = (const char*)&Kl[cur][0];
        const char* vl = (const char*)&Vl[cur][0];

        // S^T[kv-slot][q] = K . Q^T
        f32x4 st[2][4] = {};
        __builtin_amdgcn_s_setprio(1);
#pragma unroll
        for (int kk = 0; kk < 4; ++kk) {
          bf16x8 ak[4];
#pragma unroll
          for (int mf = 0; mf < 4; ++mf)
            ak[mf] = *(const bf16x8*)(kl + (mf * 16 + ln) * 256 + ((kk * 64 + g * 16) ^ ((ln & 7) << 4)));
#pragma unroll
          for (int mf = 0; mf < 4; ++mf) {
            st[0][mf] = __builtin_amdgcn_mfma_f32_16x16x32_bf16(ak[mf], bq[0][kk], st[0][mf], 0, 0, 0);
            st[1][mf] = __builtin_amdgcn_mfma_f32_16x16x32_bf16(ak[mf], bq[1][kk], st[1][mf], 0, 0, 0);
          }
        }
        __builtin_amdgcn_s_setprio(0);

        // causal mask: slot (mf,g,r) holds TRUE kv = kv0 + 32(mf>>1) + 8g + 4(mf&1) + r
        if (kv0 + 63 > qw) {
#pragma unroll
          for (int f = 0; f < 2; ++f)
#pragma unroll
            for (int mf = 0; mf < 4; ++mf)
#pragma unroll
              for (int r = 0; r < 4; ++r)
                if (kv0 + 32 * (mf >> 1) + 8 * g + 4 * (mf & 1) + r > qw + f * 16 + ln)
                  st[f][mf][r] = -INFINITY;
        }

        bf16x8 ap[2][2]; // [f][ks]
#pragma unroll
        for (int f = 0; f < 2; ++f) {
          float pmax = -INFINITY;
#pragma unroll
          for (int mf = 0; mf < 4; ++mf)
#pragma unroll
            for (int r = 0; r < 4; ++r) pmax = fmaxf(pmax, st[f][mf][r]);
          pmax = fmaxf(pmax, __shfl_xor(pmax, 16));
          pmax = fmaxf(pmax, __shfl_xor(pmax, 32));
          float msub = mrun[f];
          if (__any(pmax > mrun[f] + 8.f)) { // defer-max
            msub = fmaxf(mrun[f], pmax);
            float fac = __builtin_amdgcn_exp2f(mrun[f] - msub);
            mrun[f] = msub;
            lrun[f] *= fac;
            float fr[4];
#pragma unroll
            for (int r = 0; r < 4; ++r) fr[r] = __shfl(fac, g * 4 + r);
#pragma unroll
            for (int nf = 0; nf < 8; ++nf) {
              acc[f][nf][0] *= fr[0]; acc[f][nf][1] *= fr[1];
              acc[f][nf][2] *= fr[2]; acc[f][nf][3] *= fr[3];
            }
          }
          uint32_t Aq[4][2];
          float psum = 0.f;
#pragma unroll
          for (int mf = 0; mf < 4; ++mf) {
            float p0 = __builtin_amdgcn_exp2f(st[f][mf][0] - msub);
            float p1 = __builtin_amdgcn_exp2f(st[f][mf][1] - msub);
            float p2 = __builtin_amdgcn_exp2f(st[f][mf][2] - msub);
            float p3 = __builtin_amdgcn_exp2f(st[f][mf][3] - msub);
            psum += (p0 + p1) + (p2 + p3);
            asm("v_cvt_pk_bf16_f32 %0, %1, %2" : "=v"(Aq[mf][0]) : "v"(p0), "v"(p1));
            asm("v_cvt_pk_bf16_f32 %0, %1, %2" : "=v"(Aq[mf][1]) : "v"(p2), "v"(p3));
          }
          psum += __shfl_xor(psum, 16);
          psum += __shfl_xor(psum, 32);
          lrun[f] += psum;

          // shuffle-free routing (K-row permutation): ap[ks] = {Aq[2ks], Aq[2ks+1]}
#pragma unroll
          for (int ks = 0; ks < 2; ++ks) {
            union { uint32_t u[4]; bf16x8 v; } t;
            t.u[0] = Aq[2 * ks][0];     t.u[1] = Aq[2 * ks][1];
            t.u[2] = Aq[2 * ks + 1][0]; t.u[3] = Aq[2 * ks + 1][1];
            ap[f][ks] = t.v;
          }
        }

        __builtin_amdgcn_s_setprio(1);
#pragma unroll
        for (int nf = 0; nf < 8; ++nf) {
          int d = nf * 16 + ln;
#pragma unroll
          for (int ks = 0; ks < 2; ++ks) {
            bf16x8 bv = *(const bf16x8*)(vl + d * 128 + ((ks * 64 + g * 16) ^ ((ln & 7) << 4)));
            acc[0][nf] = __builtin_amdgcn_mfma_f32_16x16x32_bf16(ap[0][ks], bv, acc[0][nf], 0, 0, 0);
            acc[1][nf] = __builtin_amdgcn_mfma_f32_16x16x32_bf16(ap[1][ks], bv, acc[1][nf], 0, 0, 0);
          }
        }
        __builtin_amdgcn_s_setprio(0);
      }
      __syncthreads();
      cur ^= 1;
    }

    // epilogue: divide by row sum, write ctx [B, T, NH*HD]
#pragma unroll
    for (int f = 0; f < 2; ++f) {
      float inv[4];
#pragma unroll
      for (int r = 0; r < 4; ++r) inv[r] = 1.f / __shfl(lrun[f], g * 4 + r);
#pragma unroll
      for (int nf = 0; nf < 8; ++nf) {
#pragma unroll
        for (int r = 0; r < 4; ++r) {
          int qrow = qw + f * 16 + g * 4 + r;
          ctx[((size_t)(b * T_SEQ + qrow)) * H_DIM + h * HD_ + nf * 16 + ln] =
              f2b(acc[f][nf][r] * inv[r]);
        }
      }
    }
  }
#undef STAGE_KV
}

// ---------------- host launch ----------------
extern "C" void kernel_launch(void* const* d_in, const int* in_sizes, int n_in,
                              void* d_out, int out_size, void* d_ws, size_t ws_size,
                              hipStream_t stream) {
  (void)in_sizes; (void)n_in; (void)out_size; (void)ws_size;
  const float* x  = (const float*)d_in[0];
  const float* qw = (const float*)d_in[1];
  const float* qb = (const float*)d_in[2];
  const float* kw = (const float*)d_in[3];
  const float* kb = (const float*)d_in[4];
  const float* vw = (const float*)d_in[5];
  const float* vb = (const float*)d_in[6];
  const float* ow = (const float*)d_in[7];
  const float* ob = (const float*)d_in[8];

  char* ws = (char*)d_ws;
  unsigned short* xb  = (unsigned short*)(ws);              // 32 MiB (x bf16; later reused as ctx)
  unsigned short* qwb = (unsigned short*)(ws + 33554432);   // 8 MiB
  unsigned short* kwb = (unsigned short*)(ws + 41943040);
  unsigned short* vwb = (unsigned short*)(ws + 50331648);
  unsigned short* owb = (unsigned short*)(ws + 58720256);
  unsigned short* Qb  = (unsigned short*)(ws + 67108864);   // 32 MiB [B,NH,T,HD]
  unsigned short* Kb  = (unsigned short*)(ws + 100663296);  // 32 MiB (row-permuted per 64)
  unsigned short* Vtb = (unsigned short*)(ws + 134217728);  // 32 MiB [B,NH,HD,T]
  unsigned short* ctxb = xb;                                // alias: x dead after V proj

  const float cscale = 0.08838834764831845f * 1.4426950408889634f; // SCALE * log2(e)

  dim3 blk(256);
  cvt_bf16_k<<<2048, blk, 0, stream>>>(x, xb, (MTOK * H_DIM) / 4);
  cvt4_bf16_k<<<2048, blk, 0, stream>>>(qw, kw, vw, ow, qwb, kwb, vwb, owb);

  dim3 ggrid(H_DIM / 256, MTOK / 256); // (8, 32) = 256 blocks
  dim3 gblk(512);
  gemm256_k<0><<<ggrid, gblk, 0, stream>>>(xb, qwb, qb, Qb, cscale); // Q pre-scaled
  gemm256_k<3><<<ggrid, gblk, 0, stream>>>(xb, kwb, kb, Kb, 1.0f);   // K row-permuted
  gemm256_k<1><<<ggrid, gblk, 0, stream>>>(xb, vwb, vb, Vtb, 1.0f);

  attn128_k<<<dim3(512), dim3(256), 0, stream>>>(Qb, Kb, Vtb, ctxb);

  gemm256_k<2><<<ggrid, gblk, 0, stream>>>(ctxb, owb, ob, (float*)d_out, 1.0f);
}

// Round 18
// 488.219 us; speedup vs baseline: 1.0122x; 1.0122x over previous
//
#include <hip/hip_runtime.h>
#include <stdint.h>

// Problem constants
#define B_SZ 4
#define T_SEQ 2048
#define H_DIM 2048
#define NH_ 16
#define HD_ 128
#define MTOK (B_SZ * T_SEQ) // 8192

typedef __attribute__((ext_vector_type(8))) short bf16x8;
typedef __attribute__((ext_vector_type(4))) float f32x4;
typedef __attribute__((ext_vector_type(4))) unsigned short u16x4;

__device__ __forceinline__ unsigned short f2b(float f) {
  union { float f; uint32_t u; } x; x.f = f;
  uint32_t r = x.u + 0x7FFFu + ((x.u >> 16) & 1u); // RNE
  return (unsigned short)(r >> 16);
}

__device__ __forceinline__ void gload16(const void* g, void* l) {
  // width-16 global->LDS DMA; LDS dest is wave-uniform base, HW scatters lane*16
  __builtin_amdgcn_global_load_lds((const __attribute__((address_space(1))) void*)g,
                                   (__attribute__((address_space(3))) void*)l, 16, 0, 0);
}

// ---------------- f32 -> bf16 conversion ----------------
__global__ void cvt_bf16_k(const float* __restrict__ in, unsigned short* __restrict__ out, int n4) {
  for (int i = blockIdx.x * blockDim.x + threadIdx.x; i < n4; i += gridDim.x * blockDim.x) {
    float4 v = ((const float4*)in)[i];
    u16x4 o;
    o[0] = f2b(v.x); o[1] = f2b(v.y); o[2] = f2b(v.z); o[3] = f2b(v.w);
    ((u16x4*)out)[i] = o;
  }
}

// 4 weight matrices (each 1M float4 groups) in one launch; buffer = idx >> 20.
__global__ void cvt4_bf16_k(const float* __restrict__ s0, const float* __restrict__ s1,
                            const float* __restrict__ s2, const float* __restrict__ s3,
                            unsigned short* __restrict__ d0, unsigned short* __restrict__ d1,
                            unsigned short* __restrict__ d2, unsigned short* __restrict__ d3) {
  const int n4each = (H_DIM * H_DIM) / 4; // 1M
  for (int i = blockIdx.x * blockDim.x + threadIdx.x; i < 4 * n4each; i += gridDim.x * blockDim.x) {
    int sel = i >> 20, j = i & (n4each - 1);
    const float* src = sel == 0 ? s0 : sel == 1 ? s1 : sel == 2 ? s2 : s3;
    unsigned short* dst = sel == 0 ? d0 : sel == 1 ? d1 : sel == 2 ? d2 : d3;
    float4 v = ((const float4*)src)[j];
    u16x4 o;
    o[0] = f2b(v.x); o[1] = f2b(v.y); o[2] = f2b(v.z); o[3] = f2b(v.w);
    ((u16x4*)dst)[j] = o;
  }
}

// ---------------- GEMM 256x256 tile, BK=64, 8 waves (r12-verified loop) ----------
// C[m][n] = (sum_k A[m][k] * W[n][k] + bias[n]) * oscale(MODE0 only)
// MODE 0: bf16 out, scatter to [B, NH, T, HD]   (Q pre-scaled) — LDS-coalesced epi
// MODE 3: bf16 out, [B, NH, T, HD] + intra-64 row permutation (K) — LDS-coalesced epi
// MODE 1: bf16 out, scatter to [B, NH, HD, T]   (V transposed, linear kv)
// MODE 2: f32 out, row-major [M, N]             (final projection)
template <int MODE>
__global__ __launch_bounds__(512, 2) void gemm256_k(const unsigned short* __restrict__ A,
                                                    const unsigned short* __restrict__ W,
                                                    const float* __restrict__ bias,
                                                    void* __restrict__ outp,
                                                    float oscale) {
  constexpr int K = H_DIM;   // 2048
  constexpr int NT = K / 64; // 32 K-tiles
  __shared__ __align__(16) unsigned short Al[2][256 * 64];
  __shared__ __align__(16) unsigned short Bl[2][256 * 64];

  const int tid = threadIdx.x;
  const int w = tid >> 6, l = tid & 63;
  const int g = l >> 4, ln = l & 15;
  const int wr = w >> 2, wc = w & 3;

  const int bid = blockIdx.x + gridDim.x * blockIdx.y;
  const int fid = ((bid & 7) << 5) | (bid >> 3);
  const int col0 = (fid & 7) * 256;
  const int row0 = (fid >> 3) * 256;

  const char* Ag = (const char*)A;
  const char* Wg = (const char*)W;

  const int srow = l >> 3;
  const int sbyte = ((l & 7) * 16) ^ (srow << 4);

#define ST_A(t2, b2, c)                                                                 \
  gload16(Ag + (((size_t)(row0 + (c) * 8 + srow)) * K + (t2) * 64) * 2 + sbyte,         \
          (char*)&Al[b2][0] + (c) * 1024)
#define ST_B(t2, b2, c)                                                                 \
  gload16(Wg + (((size_t)(col0 + (c) * 8 + srow)) * K + (t2) * 64) * 2 + sbyte,         \
          (char*)&Bl[b2][0] + (c) * 1024)
#define STAGE_A0(t2, b2) do { ST_A(t2, b2, w);  ST_A(t2, b2, 16 + w); } while (0)
#define STAGE_A1(t2, b2) do { ST_A(t2, b2, 8 + w); ST_A(t2, b2, 24 + w); } while (0)
#define STAGE_B0(t2, b2) do { int c_ = (w >> 2) * 8 + (w & 3); ST_B(t2, b2, c_); ST_B(t2, b2, 16 + c_); } while (0)
#define STAGE_B1(t2, b2) do { int c_ = (w >> 2) * 8 + 4 + (w & 3); ST_B(t2, b2, c_); ST_B(t2, b2, 16 + c_); } while (0)

  f32x4 acc[8][4] = {};
  bf16x8 aF[4][2];
  bf16x8 bF[2][2][2];

#define READ_A(mh)                                                                      \
  _Pragma("unroll") for (int mf = 0; mf < 4; ++mf)                                      \
  _Pragma("unroll") for (int ks = 0; ks < 2; ++ks) {                                    \
    int row_ = wr * 128 + (mh) * 64 + mf * 16 + ln;                                     \
    aF[mf][ks] = *(const bf16x8*)((const char*)Ab + row_ * 128 +                        \
                                  ((ks * 64 + g * 16) ^ ((ln & 7) << 4)));              \
  }
#define READ_B(nh)                                                                      \
  _Pragma("unroll") for (int nf = 0; nf < 2; ++nf)                                      \
  _Pragma("unroll") for (int ks = 0; ks < 2; ++ks) {                                    \
    int row_ = wc * 64 + (nh) * 32 + nf * 16 + ln;                                      \
    bF[nh][nf][ks] = *(const bf16x8*)((const char*)Bb + row_ * 128 +                    \
                                      ((ks * 64 + g * 16) ^ ((ln & 7) << 4)));          \
  }
#define MFMA_PHASE(mh, nh)                                                              \
  do {                                                                                  \
    __builtin_amdgcn_s_setprio(1);                                                      \
    _Pragma("unroll") for (int mf = 0; mf < 4; ++mf)                                    \
    _Pragma("unroll") for (int nf = 0; nf < 2; ++nf)                                    \
    _Pragma("unroll") for (int ks = 0; ks < 2; ++ks)                                    \
      acc[(mh) * 4 + mf][(nh) * 2 + nf] = __builtin_amdgcn_mfma_f32_16x16x32_bf16(      \
          aF[mf][ks], bF[nh][nf][ks], acc[(mh) * 4 + mf][(nh) * 2 + nf], 0, 0, 0);      \
    __builtin_amdgcn_s_setprio(0);                                                      \
  } while (0)
#define WAITL()  asm volatile("s_waitcnt lgkmcnt(0)" ::: "memory")
#define BARRIER() asm volatile("s_barrier" ::: "memory")

  STAGE_A0(0, 0); STAGE_B0(0, 0); STAGE_B1(0, 0); STAGE_A1(0, 0);
  STAGE_A0(1, 1); STAGE_B0(1, 1); STAGE_B1(1, 1); STAGE_A1(1, 1);
  asm volatile("s_waitcnt vmcnt(8)" ::: "memory");
  BARRIER();

#pragma unroll 1
  for (int t = 0; t < NT; ++t) {
    const int buf = t & 1;
    const unsigned short* Ab = &Al[buf][0];
    const unsigned short* Bb = &Bl[buf][0];
    READ_A(0); READ_B(0);
    if (t >= 1 && t + 1 < NT) STAGE_A1(t + 1, (t + 1) & 1);
    BARRIER();
    MFMA_PHASE(0, 0);
    BARRIER();
    READ_B(1);
    if (t + 2 < NT) STAGE_A0(t + 2, buf);
    BARRIER();
    MFMA_PHASE(0, 1);
    BARRIER();
    READ_A(1);
    if (t + 2 < NT) STAGE_B0(t + 2, buf);
    BARRIER();
    MFMA_PHASE(1, 0);
    BARRIER();
    if (t + 2 < NT) {
      STAGE_B1(t + 2, buf);
      asm volatile("s_waitcnt vmcnt(6)" ::: "memory");
    } else {
      asm volatile("s_waitcnt vmcnt(0)" ::: "memory");
    }
    BARRIER();
    MFMA_PHASE(1, 1);
    BARRIER();
  }

  // ---- epilogue ----
  if constexpr (MODE == 0 || MODE == 3) {
    // LDS-transposed coalesced epilogue: 4 chunks of 64 C-rows. Owner waves
    // (wr == ch>>1) deposit f2b(acc+bias) into a stride-260 bf16 scratch
    // (bank = 8g+2r+8ni+(ln>>1): all 32 banks, 2 lanes each -> conflict-free),
    // then all 512 threads store 8 passes of 64-lane x 8B runs (256B/head, fully
    // coalesced). MODE 3 applies the intra-64 kv row permutation on t at store.
    unsigned short* out = (unsigned short*)outp;
    unsigned short* lbuf = &Al[0][0]; // 64 x 260 bf16 = 33.3 KB, fits Al
    const int rw = tid >> 6, l8 = tid & 63;
#pragma unroll 1
    for (int ch = 0; ch < 4; ++ch) {
      if (wr == (ch >> 1)) {
        const int mh = ch & 1;
#pragma unroll
        for (int mi = 0; mi < 4; ++mi) {
#pragma unroll
          for (int ni = 0; ni < 4; ++ni) {
            int n = col0 + wc * 64 + ni * 16 + ln;
            float bv = bias[n];
#pragma unroll
            for (int r = 0; r < 4; ++r)
              lbuf[(mi * 16 + 4 * g + r) * 260 + wc * 64 + ni * 16 + ln] =
                  f2b((acc[mh * 4 + mi][ni][r] + bv) * oscale);
          }
        }
      }
      WAITL();
      BARRIER();
#pragma unroll
      for (int p = 0; p < 8; ++p) {
        int row = p * 8 + rw;                         // 0..63
        int m = row0 + (ch >> 1) * 128 + (ch & 1) * 64 + row;
        int b = m >> 11, t = m & 2047;
        if constexpr (MODE == 3) {
          int tl = t & 63;
          t = (t & ~63) | ((tl >> 5) * 32 + ((tl >> 2) & 1) * 16 + ((tl >> 3) & 3) * 4 + (tl & 3));
        }
        int nn = l8 * 4;                              // col (bf16 units) 0..252
        int h = (col0 + nn) >> 7, d = nn & 127;
        *(uint2*)&out[(((size_t)(b * NH_ + h)) * T_SEQ + t) * HD_ + d] =
            *(const uint2*)&lbuf[row * 260 + nn];
      }
      BARRIER();
    }
  } else {
#pragma unroll
    for (int mi = 0; mi < 8; ++mi) {
#pragma unroll
      for (int ni = 0; ni < 4; ++ni) {
        int n = col0 + wc * 64 + ni * 16 + ln;
        float bv = bias[n];
        if constexpr (MODE == 2) {
          float* out = (float*)outp;
#pragma unroll
          for (int r = 0; r < 4; ++r) {
            int m = row0 + wr * 128 + mi * 16 + 4 * g + r;
            out[(size_t)m * H_DIM + n] = acc[mi][ni][r] + bv;
          }
        } else { // MODE 1: V transposed [B, NH, HD, T], linear kv columns
          unsigned short* out = (unsigned short*)outp;
          int h = n >> 7, d = n & 127;
          int m0 = row0 + wr * 128 + mi * 16 + 4 * g;
          int b = m0 >> 11, t0 = m0 & 2047;
          u16x4 pk;
#pragma unroll
          for (int r = 0; r < 4; ++r) pk[r] = f2b(acc[mi][ni][r] + bv);
          *(u16x4*)&out[(((size_t)(b * NH_ + h)) * HD_ + d) * T_SEQ + t0] = pk;
        }
      }
    }
  }
#undef ST_A
#undef ST_B
#undef STAGE_A0
#undef STAGE_A1
#undef STAGE_B0
#undef STAGE_B1
#undef READ_A
#undef READ_B
#undef MFMA_PHASE
#undef WAITL
#undef BARRIER
}

// ---------------- causal flash attention (r16-verified, ~104 us) ----------------
// QBLK=128 (4 waves), 512 blocks, serial q-tile pair (15-pr, pr) -> 34 iters each;
// 2 blocks/CU. K rows pre-permuted (MODE 3) -> shuffle-free P routing; in-reg P.
__global__ __launch_bounds__(256, 2) void attn128_k(const unsigned short* __restrict__ Q,
                                                    const unsigned short* __restrict__ Kg,
                                                    const unsigned short* __restrict__ Vt,
                                                    unsigned short* __restrict__ ctx) {
  __shared__ __align__(16) unsigned short Kl[2][64 * 128]; // [kv-slot][k] swizzled rows (256B)
  __shared__ __align__(16) unsigned short Vl[2][128 * 64]; // [d][kv] swizzled rows (128B)

  const int tid = threadIdx.x;
  const int w = tid >> 6, l = tid & 63;   // w: 0..3
  const int g = l >> 4, ln = l & 15;

  // XCD grouping: 512 blocks -> 64 consecutive per XCD; each bh's 8 blocks on one XCD
  const int flat = ((blockIdx.x & 7) << 6) | (blockIdx.x >> 3);
  const int bh = flat >> 3;  // 0..63
  const int pr = flat & 7;   // 0..7 -> q-tile pair (15-pr, pr)

  const char* kbase = (const char*)(Kg + (size_t)bh * T_SEQ * HD_);
  const char* vbase = (const char*)(Vt + (size_t)bh * HD_ * T_SEQ);
  const int b = bh >> 4, h = bh & 15;

#define STAGE_KV(bufi, ktile) do {                                                    \
    int kv0_ = (ktile) * 64;                                                          \
    _Pragma("unroll")                                                                 \
    for (int i_ = 0; i_ < 4; ++i_) {                                                  \
      int c_ = w * 4 + i_;                                                            \
      int kvr_ = c_ * 4 + g;                                                          \
      gload16(kbase + ((size_t)(kv0_ + kvr_) * HD_) * 2 + ((ln * 16) ^ ((kvr_ & 7) << 4)), \
              (char*)&Kl[bufi][0] + c_ * 1024);                                       \
      int d_ = c_ * 8 + (l >> 3);                                                     \
      gload16(vbase + ((size_t)d_ * T_SEQ + kv0_) * 2 + (((l & 7) * 16) ^ ((d_ & 7) << 4)), \
              (char*)&Vl[bufi][0] + c_ * 1024);                                       \
    } } while (0)

#pragma unroll 1
  for (int half = 0; half < 2; ++half) {
    const int qt = half ? pr : (15 - pr); // heavy 128-row tile first
    const int q0 = qt << 7;
    const int qw = q0 + w * 32;           // wave's first q row

    bf16x8 bq[2][4];
#pragma unroll
    for (int f = 0; f < 2; ++f)
#pragma unroll
      for (int kk = 0; kk < 4; ++kk)
        bq[f][kk] = *(const bf16x8*)(Q + ((size_t)bh * T_SEQ + qw + f * 16 + ln) * HD_ + kk * 32 + g * 8);

    f32x4 acc[2][8] = {};
    float mrun[2] = {-INFINITY, -INFINITY};
    float lrun[2] = {0.f, 0.f};

    const int nt = (qt + 1) * 2;

    STAGE_KV(0, 0);
    __syncthreads();
    int cur = 0;

#pragma unroll 1
    for (int kt = 0; kt < nt; ++kt) {
      if (kt + 1 < nt) STAGE_KV(cur ^ 1, kt + 1); // prefetch overlaps compute
      const int kv0 = kt * 64;
      if (kv0 <= qw + 31) { // causal wave-skip (barriers stay outside)
        const char* kl = (const char*)&Kl[cur][0];
        const char* vl = (const char*)&Vl[cur][0];

        // S^T[kv-slot][q] = K . Q^T
        f32x4 st[2][4] = {};
        __builtin_amdgcn_s_setprio(1);
#pragma unroll
        for (int kk = 0; kk < 4; ++kk) {
          bf16x8 ak[4];
#pragma unroll
          for (int mf = 0; mf < 4; ++mf)
            ak[mf] = *(const bf16x8*)(kl + (mf * 16 + ln) * 256 + ((kk * 64 + g * 16) ^ ((ln & 7) << 4)));
#pragma unroll
          for (int mf = 0; mf < 4; ++mf) {
            st[0][mf] = __builtin_amdgcn_mfma_f32_16x16x32_bf16(ak[mf], bq[0][kk], st[0][mf], 0, 0, 0);
            st[1][mf] = __builtin_amdgcn_mfma_f32_16x16x32_bf16(ak[mf], bq[1][kk], st[1][mf], 0, 0, 0);
          }
        }
        __builtin_amdgcn_s_setprio(0);

        // causal mask: slot (mf,g,r) holds TRUE kv = kv0 + 32(mf>>1) + 8g + 4(mf&1) + r
        if (kv0 + 63 > qw) {
#pragma unroll
          for (int f = 0; f < 2; ++f)
#pragma unroll
            for (int mf = 0; mf < 4; ++mf)
#pragma unroll
              for (int r = 0; r < 4; ++r)
                if (kv0 + 32 * (mf >> 1) + 8 * g + 4 * (mf & 1) + r > qw + f * 16 + ln)
                  st[f][mf][r] = -INFINITY;
        }

        bf16x8 ap[2][2]; // [f][ks]
#pragma unroll
        for (int f = 0; f < 2; ++f) {
          float pmax = -INFINITY;
#pragma unroll
          for (int mf = 0; mf < 4; ++mf)
#pragma unroll
            for (int r = 0; r < 4; ++r) pmax = fmaxf(pmax, st[f][mf][r]);
          pmax = fmaxf(pmax, __shfl_xor(pmax, 16));
          pmax = fmaxf(pmax, __shfl_xor(pmax, 32));
          float msub = mrun[f];
          if (__any(pmax > mrun[f] + 8.f)) { // defer-max
            msub = fmaxf(mrun[f], pmax);
            float fac = __builtin_amdgcn_exp2f(mrun[f] - msub);
            mrun[f] = msub;
            lrun[f] *= fac;
            float fr[4];
#pragma unroll
            for (int r = 0; r < 4; ++r) fr[r] = __shfl(fac, g * 4 + r);
#pragma unroll
            for (int nf = 0; nf < 8; ++nf) {
              acc[f][nf][0] *= fr[0]; acc[f][nf][1] *= fr[1];
              acc[f][nf][2] *= fr[2]; acc[f][nf][3] *= fr[3];
            }
          }
          uint32_t Aq[4][2];
          float psum = 0.f;
#pragma unroll
          for (int mf = 0; mf < 4; ++mf) {
            float p0 = __builtin_amdgcn_exp2f(st[f][mf][0] - msub);
            float p1 = __builtin_amdgcn_exp2f(st[f][mf][1] - msub);
            float p2 = __builtin_amdgcn_exp2f(st[f][mf][2] - msub);
            float p3 = __builtin_amdgcn_exp2f(st[f][mf][3] - msub);
            psum += (p0 + p1) + (p2 + p3);
            asm("v_cvt_pk_bf16_f32 %0, %1, %2" : "=v"(Aq[mf][0]) : "v"(p0), "v"(p1));
            asm("v_cvt_pk_bf16_f32 %0, %1, %2" : "=v"(Aq[mf][1]) : "v"(p2), "v"(p3));
          }
          psum += __shfl_xor(psum, 16);
          psum += __shfl_xor(psum, 32);
          lrun[f] += psum;

          // shuffle-free routing (K-row permutation): ap[ks] = {Aq[2ks], Aq[2ks+1]}
#pragma unroll
          for (int ks = 0; ks < 2; ++ks) {
            union { uint32_t u[4]; bf16x8 v; } t;
            t.u[0] = Aq[2 * ks][0];     t.u[1] = Aq[2 * ks][1];
            t.u[2] = Aq[2 * ks + 1][0]; t.u[3] = Aq[2 * ks + 1][1];
            ap[f][ks] = t.v;
          }
        }

        __builtin_amdgcn_s_setprio(1);
#pragma unroll
        for (int nf = 0; nf < 8; ++nf) {
          int d = nf * 16 + ln;
#pragma unroll
          for (int ks = 0; ks < 2; ++ks) {
            bf16x8 bv = *(const bf16x8*)(vl + d * 128 + ((ks * 64 + g * 16) ^ ((ln & 7) << 4)));
            acc[0][nf] = __builtin_amdgcn_mfma_f32_16x16x32_bf16(ap[0][ks], bv, acc[0][nf], 0, 0, 0);
            acc[1][nf] = __builtin_amdgcn_mfma_f32_16x16x32_bf16(ap[1][ks], bv, acc[1][nf], 0, 0, 0);
          }
        }
        __builtin_amdgcn_s_setprio(0);
      }
      __syncthreads();
      cur ^= 1;
    }

    // epilogue: divide by row sum, write ctx [B, T, NH*HD]
#pragma unroll
    for (int f = 0; f < 2; ++f) {
      float inv[4];
#pragma unroll
      for (int r = 0; r < 4; ++r) inv[r] = 1.f / __shfl(lrun[f], g * 4 + r);
#pragma unroll
      for (int nf = 0; nf < 8; ++nf) {
#pragma unroll
        for (int r = 0; r < 4; ++r) {
          int qrow = qw + f * 16 + g * 4 + r;
          ctx[((size_t)(b * T_SEQ + qrow)) * H_DIM + h * HD_ + nf * 16 + ln] =
              f2b(acc[f][nf][r] * inv[r]);
        }
      }
    }
  }
#undef STAGE_KV
}

// ---------------- host launch ----------------
extern "C" void kernel_launch(void* const* d_in, const int* in_sizes, int n_in,
                              void* d_out, int out_size, void* d_ws, size_t ws_size,
                              hipStream_t stream) {
  (void)in_sizes; (void)n_in; (void)out_size; (void)ws_size;
  const float* x  = (const float*)d_in[0];
  const float* qw = (const float*)d_in[1];
  const float* qb = (const float*)d_in[2];
  const float* kw = (const float*)d_in[3];
  const float* kb = (const float*)d_in[4];
  const float* vw = (const float*)d_in[5];
  const float* vb = (const float*)d_in[6];
  const float* ow = (const float*)d_in[7];
  const float* ob = (const float*)d_in[8];

  char* ws = (char*)d_ws;
  unsigned short* xb  = (unsigned short*)(ws);              // 32 MiB (x bf16; later reused as ctx)
  unsigned short* qwb = (unsigned short*)(ws + 33554432);   // 8 MiB
  unsigned short* kwb = (unsigned short*)(ws + 41943040);
  unsigned short* vwb = (unsigned short*)(ws + 50331648);
  unsigned short* owb = (unsigned short*)(ws + 58720256);
  unsigned short* Qb  = (unsigned short*)(ws + 67108864);   // 32 MiB [B,NH,T,HD]
  unsigned short* Kb  = (unsigned short*)(ws + 100663296);  // 32 MiB (row-permuted per 64)
  unsigned short* Vtb = (unsigned short*)(ws + 134217728);  // 32 MiB [B,NH,HD,T]
  unsigned short* ctxb = xb;                                // alias: x dead after V proj

  const float cscale = 0.08838834764831845f * 1.4426950408889634f; // SCALE * log2(e)

  dim3 blk(256);
  cvt_bf16_k<<<2048, blk, 0, stream>>>(x, xb, (MTOK * H_DIM) / 4);
  cvt4_bf16_k<<<2048, blk, 0, stream>>>(qw, kw, vw, ow, qwb, kwb, vwb, owb);

  dim3 ggrid(H_DIM / 256, MTOK / 256); // (8, 32) = 256 blocks
  dim3 gblk(512);
  gemm256_k<0><<<ggrid, gblk, 0, stream>>>(xb, qwb, qb, Qb, cscale); // Q pre-scaled
  gemm256_k<3><<<ggrid, gblk, 0, stream>>>(xb, kwb, kb, Kb, 1.0f);   // K row-permuted
  gemm256_k<1><<<ggrid, gblk, 0, stream>>>(xb, vwb, vb, Vtb, 1.0f);

  attn128_k<<<dim3(512), dim3(256), 0, stream>>>(Qb, Kb, Vtb, ctxb);

  gemm256_k<2><<<ggrid, gblk, 0, stream>>>(ctxb, owb, ob, (float*)d_out, 1.0f);
}

// Round 19
// 380.788 us; speedup vs baseline: 1.2977x; 1.2821x over previous
//
#include <hip/hip_runtime.h>
#include <stdint.h>

// Problem constants
#define B_SZ 4
#define T_SEQ 2048
#define H_DIM 2048
#define NH_ 16
#define HD_ 128
#define MTOK (B_SZ * T_SEQ) // 8192

typedef __attribute__((ext_vector_type(8))) short bf16x8;
typedef __attribute__((ext_vector_type(4))) float f32x4;
typedef __attribute__((ext_vector_type(4))) unsigned short u16x4;

__device__ __forceinline__ unsigned short f2b(float f) {
  union { float f; uint32_t u; } x; x.f = f;
  uint32_t r = x.u + 0x7FFFu + ((x.u >> 16) & 1u); // RNE
  return (unsigned short)(r >> 16);
}

__device__ __forceinline__ void gload16(const void* g, void* l) {
  // width-16 global->LDS DMA; LDS dest is wave-uniform base, HW scatters lane*16
  __builtin_amdgcn_global_load_lds((const __attribute__((address_space(1))) void*)g,
                                   (__attribute__((address_space(3))) void*)l, 16, 0, 0);
}

// ---------------- f32 -> bf16 conversion ----------------
__global__ void cvt_bf16_k(const float* __restrict__ in, unsigned short* __restrict__ out, int n4) {
  for (int i = blockIdx.x * blockDim.x + threadIdx.x; i < n4; i += gridDim.x * blockDim.x) {
    float4 v = ((const float4*)in)[i];
    u16x4 o;
    o[0] = f2b(v.x); o[1] = f2b(v.y); o[2] = f2b(v.z); o[3] = f2b(v.w);
    ((u16x4*)out)[i] = o;
  }
}

// 4 weight matrices (each 1M float4 groups) in one launch; buffer = idx >> 20.
__global__ void cvt4_bf16_k(const float* __restrict__ s0, const float* __restrict__ s1,
                            const float* __restrict__ s2, const float* __restrict__ s3,
                            unsigned short* __restrict__ d0, unsigned short* __restrict__ d1,
                            unsigned short* __restrict__ d2, unsigned short* __restrict__ d3) {
  const int n4each = (H_DIM * H_DIM) / 4; // 1M
  for (int i = blockIdx.x * blockDim.x + threadIdx.x; i < 4 * n4each; i += gridDim.x * blockDim.x) {
    int sel = i >> 20, j = i & (n4each - 1);
    const float* src = sel == 0 ? s0 : sel == 1 ? s1 : sel == 2 ? s2 : s3;
    unsigned short* dst = sel == 0 ? d0 : sel == 1 ? d1 : sel == 2 ? d2 : d3;
    float4 v = ((const float4*)src)[j];
    u16x4 o;
    o[0] = f2b(v.x); o[1] = f2b(v.y); o[2] = f2b(v.z); o[3] = f2b(v.w);
    ((u16x4*)dst)[j] = o;
  }
}

// ---------------- GEMM 256x256 tile, BK=64, 8 waves (r12-verified) ----------
// C[m][n] = (sum_k A[m][k] * W[n][k] + bias[n]) * oscale(MODE0 only)
// MODE 0: bf16 out, scatter to [B, NH, T, HD]   (Q pre-scaled)
// MODE 3: bf16 out, scatter to [B, NH, T, HD] with intra-64 row permutation (K)
// MODE 1: bf16 out, scatter to [B, NH, HD, T]   (V transposed, linear kv)
// MODE 2: f32 out, row-major [M, N]             (final projection)
template <int MODE>
__global__ __launch_bounds__(512, 2) void gemm256_k(const unsigned short* __restrict__ A,
                                                    const unsigned short* __restrict__ W,
                                                    const float* __restrict__ bias,
                                                    void* __restrict__ outp,
                                                    float oscale) {
  constexpr int K = H_DIM;   // 2048
  constexpr int NT = K / 64; // 32 K-tiles
  __shared__ __align__(16) unsigned short Al[2][256 * 64];
  __shared__ __align__(16) unsigned short Bl[2][256 * 64];

  const int tid = threadIdx.x;
  const int w = tid >> 6, l = tid & 63;
  const int g = l >> 4, ln = l & 15;
  const int wr = w >> 2, wc = w & 3;

  const int bid = blockIdx.x + gridDim.x * blockIdx.y;
  const int fid = ((bid & 7) << 5) | (bid >> 3);
  const int col0 = (fid & 7) * 256;
  const int row0 = (fid >> 3) * 256;

  const char* Ag = (const char*)A;
  const char* Wg = (const char*)W;

  const int srow = l >> 3;
  const int sbyte = ((l & 7) * 16) ^ (srow << 4);

#define ST_A(t2, b2, c)                                                                 \
  gload16(Ag + (((size_t)(row0 + (c) * 8 + srow)) * K + (t2) * 64) * 2 + sbyte,         \
          (char*)&Al[b2][0] + (c) * 1024)
#define ST_B(t2, b2, c)                                                                 \
  gload16(Wg + (((size_t)(col0 + (c) * 8 + srow)) * K + (t2) * 64) * 2 + sbyte,         \
          (char*)&Bl[b2][0] + (c) * 1024)
#define STAGE_A0(t2, b2) do { ST_A(t2, b2, w);  ST_A(t2, b2, 16 + w); } while (0)
#define STAGE_A1(t2, b2) do { ST_A(t2, b2, 8 + w); ST_A(t2, b2, 24 + w); } while (0)
#define STAGE_B0(t2, b2) do { int c_ = (w >> 2) * 8 + (w & 3); ST_B(t2, b2, c_); ST_B(t2, b2, 16 + c_); } while (0)
#define STAGE_B1(t2, b2) do { int c_ = (w >> 2) * 8 + 4 + (w & 3); ST_B(t2, b2, c_); ST_B(t2, b2, 16 + c_); } while (0)

  f32x4 acc[8][4] = {};
  bf16x8 aF[4][2];
  bf16x8 bF[2][2][2];

#define READ_A(mh)                                                                      \
  _Pragma("unroll") for (int mf = 0; mf < 4; ++mf)                                      \
  _Pragma("unroll") for (int ks = 0; ks < 2; ++ks) {                                    \
    int row_ = wr * 128 + (mh) * 64 + mf * 16 + ln;                                     \
    aF[mf][ks] = *(const bf16x8*)((const char*)Ab + row_ * 128 +                        \
                                  ((ks * 64 + g * 16) ^ ((ln & 7) << 4)));              \
  }
#define READ_B(nh)                                                                      \
  _Pragma("unroll") for (int nf = 0; nf < 2; ++nf)                                      \
  _Pragma("unroll") for (int ks = 0; ks < 2; ++ks) {                                    \
    int row_ = wc * 64 + (nh) * 32 + nf * 16 + ln;                                      \
    bF[nh][nf][ks] = *(const bf16x8*)((const char*)Bb + row_ * 128 +                    \
                                      ((ks * 64 + g * 16) ^ ((ln & 7) << 4)));          \
  }
#define MFMA_PHASE(mh, nh)                                                              \
  do {                                                                                  \
    __builtin_amdgcn_s_setprio(1);                                                      \
    _Pragma("unroll") for (int mf = 0; mf < 4; ++mf)                                    \
    _Pragma("unroll") for (int nf = 0; nf < 2; ++nf)                                    \
    _Pragma("unroll") for (int ks = 0; ks < 2; ++ks)                                    \
      acc[(mh) * 4 + mf][(nh) * 2 + nf] = __builtin_amdgcn_mfma_f32_16x16x32_bf16(      \
          aF[mf][ks], bF[nh][nf][ks], acc[(mh) * 4 + mf][(nh) * 2 + nf], 0, 0, 0);      \
    __builtin_amdgcn_s_setprio(0);                                                      \
  } while (0)
#define BARRIER() asm volatile("s_barrier" ::: "memory")

  STAGE_A0(0, 0); STAGE_B0(0, 0); STAGE_B1(0, 0); STAGE_A1(0, 0);
  STAGE_A0(1, 1); STAGE_B0(1, 1); STAGE_B1(1, 1); STAGE_A1(1, 1);
  asm volatile("s_waitcnt vmcnt(8)" ::: "memory");
  BARRIER();

#pragma unroll 1
  for (int t = 0; t < NT; ++t) {
    const int buf = t & 1;
    const unsigned short* Ab = &Al[buf][0];
    const unsigned short* Bb = &Bl[buf][0];
    READ_A(0); READ_B(0);
    if (t >= 1 && t + 1 < NT) STAGE_A1(t + 1, (t + 1) & 1);
    BARRIER();
    MFMA_PHASE(0, 0);
    BARRIER();
    READ_B(1);
    if (t + 2 < NT) STAGE_A0(t + 2, buf);
    BARRIER();
    MFMA_PHASE(0, 1);
    BARRIER();
    READ_A(1);
    if (t + 2 < NT) STAGE_B0(t + 2, buf);
    BARRIER();
    MFMA_PHASE(1, 0);
    BARRIER();
    if (t + 2 < NT) {
      STAGE_B1(t + 2, buf);
      asm volatile("s_waitcnt vmcnt(6)" ::: "memory");
    } else {
      asm volatile("s_waitcnt vmcnt(0)" ::: "memory");
    }
    BARRIER();
    MFMA_PHASE(1, 1);
    BARRIER();
  }

#pragma unroll
  for (int mi = 0; mi < 8; ++mi) {
#pragma unroll
    for (int ni = 0; ni < 4; ++ni) {
      int n = col0 + wc * 64 + ni * 16 + ln;
      float bv = bias[n];
      if constexpr (MODE == 2) {
        float* out = (float*)outp;
#pragma unroll
        for (int r = 0; r < 4; ++r) {
          int m = row0 + wr * 128 + mi * 16 + 4 * g + r;
          out[(size_t)m * H_DIM + n] = acc[mi][ni][r] + bv;
        }
      } else if constexpr (MODE == 0) {
        unsigned short* out = (unsigned short*)outp;
        int h = n >> 7, d = n & 127;
#pragma unroll
        for (int r = 0; r < 4; ++r) {
          int m = row0 + wr * 128 + mi * 16 + 4 * g + r;
          int b = m >> 11, tt = m & 2047;
          out[(((size_t)(b * NH_ + h)) * T_SEQ + tt) * HD_ + d] = f2b((acc[mi][ni][r] + bv) * oscale);
        }
      } else if constexpr (MODE == 3) {
        // K: permute rows within each 64-block; slot c holds true kv
        // sigma(c)=32(c>>5)+8((c>>2)&3)+4((c>>4)&1)+(c&3); store row t at sigma^{-1}(t).
        unsigned short* out = (unsigned short*)outp;
        int h = n >> 7, d = n & 127;
#pragma unroll
        for (int r = 0; r < 4; ++r) {
          int m = row0 + wr * 128 + mi * 16 + 4 * g + r;
          int b = m >> 11, tt = m & 2047;
          int tl = tt & 63;
          int tp = (tt & ~63) | ((tl >> 5) * 32 + ((tl >> 2) & 1) * 16 + ((tl >> 3) & 3) * 4 + (tl & 3));
          out[(((size_t)(b * NH_ + h)) * T_SEQ + tp) * HD_ + d] = f2b(acc[mi][ni][r] + bv);
        }
      } else { // MODE 1: V transposed [B, NH, HD, T], linear kv columns
        unsigned short* out = (unsigned short*)outp;
        int h = n >> 7, d = n & 127;
        int m0 = row0 + wr * 128 + mi * 16 + 4 * g;
        int b = m0 >> 11, t0 = m0 & 2047;
        u16x4 pk;
#pragma unroll
        for (int r = 0; r < 4; ++r) pk[r] = f2b(acc[mi][ni][r] + bv);
        *(u16x4*)&out[(((size_t)(b * NH_ + h)) * HD_ + d) * T_SEQ + t0] = pk;
      }
    }
  }
#undef ST_A
#undef ST_B
#undef STAGE_A0
#undef STAGE_A1
#undef STAGE_B0
#undef STAGE_B1
#undef READ_A
#undef READ_B
#undef MFMA_PHASE
#undef BARRIER
}

// ---------------- causal flash attention (r16-verified, ~104 us) ----------------
// QBLK=128 (4 waves), 512 blocks, serial q-tile pair (15-pr, pr) -> 34 iters each;
// 2 blocks/CU. K rows pre-permuted (MODE 3) -> shuffle-free P routing; in-reg P.
__global__ __launch_bounds__(256, 2) void attn128_k(const unsigned short* __restrict__ Q,
                                                    const unsigned short* __restrict__ Kg,
                                                    const unsigned short* __restrict__ Vt,
                                                    unsigned short* __restrict__ ctx) {
  __shared__ __align__(16) unsigned short Kl[2][64 * 128]; // [kv-slot][k] swizzled rows (256B)
  __shared__ __align__(16) unsigned short Vl[2][128 * 64]; // [d][kv] swizzled rows (128B)

  const int tid = threadIdx.x;
  const int w = tid >> 6, l = tid & 63;   // w: 0..3
  const int g = l >> 4, ln = l & 15;

  // XCD grouping: 512 blocks -> 64 consecutive per XCD; each bh's 8 blocks on one XCD
  const int flat = ((blockIdx.x & 7) << 6) | (blockIdx.x >> 3);
  const int bh = flat >> 3;  // 0..63
  const int pr = flat & 7;   // 0..7 -> q-tile pair (15-pr, pr)

  const char* kbase = (const char*)(Kg + (size_t)bh * T_SEQ * HD_);
  const char* vbase = (const char*)(Vt + (size_t)bh * HD_ * T_SEQ);
  const int b = bh >> 4, h = bh & 15;

#define STAGE_KV(bufi, ktile) do {                                                    \
    int kv0_ = (ktile) * 64;                                                          \
    _Pragma("unroll")                                                                 \
    for (int i_ = 0; i_ < 4; ++i_) {                                                  \
      int c_ = w * 4 + i_;                                                            \
      int kvr_ = c_ * 4 + g;                                                          \
      gload16(kbase + ((size_t)(kv0_ + kvr_) * HD_) * 2 + ((ln * 16) ^ ((kvr_ & 7) << 4)), \
              (char*)&Kl[bufi][0] + c_ * 1024);                                       \
      int d_ = c_ * 8 + (l >> 3);                                                     \
      gload16(vbase + ((size_t)d_ * T_SEQ + kv0_) * 2 + (((l & 7) * 16) ^ ((d_ & 7) << 4)), \
              (char*)&Vl[bufi][0] + c_ * 1024);                                       \
    } } while (0)

#pragma unroll 1
  for (int half = 0; half < 2; ++half) {
    const int qt = half ? pr : (15 - pr); // heavy 128-row tile first
    const int q0 = qt << 7;
    const int qw = q0 + w * 32;           // wave's first q row

    bf16x8 bq[2][4];
#pragma unroll
    for (int f = 0; f < 2; ++f)
#pragma unroll
      for (int kk = 0; kk < 4; ++kk)
        bq[f][kk] = *(const bf16x8*)(Q + ((size_t)bh * T_SEQ + qw + f * 16 + ln) * HD_ + kk * 32 + g * 8);

    f32x4 acc[2][8] = {};
    float mrun[2] = {-INFINITY, -INFINITY};
    float lrun[2] = {0.f, 0.f};

    const int nt = (qt + 1) * 2;

    STAGE_KV(0, 0);
    __syncthreads();
    int cur = 0;

#pragma unroll 1
    for (int kt = 0; kt < nt; ++kt) {
      if (kt + 1 < nt) STAGE_KV(cur ^ 1, kt + 1); // prefetch overlaps compute
      const int kv0 = kt * 64;
      if (kv0 <= qw + 31) { // causal wave-skip (barriers stay outside)
        const char* kl = (const char*)&Kl[cur][0];
        const char* vl = (const char*)&Vl[cur][0];

        // S^T[kv-slot][q] = K . Q^T
        f32x4 st[2][4] = {};
        __builtin_amdgcn_s_setprio(1);
#pragma unroll
        for (int kk = 0; kk < 4; ++kk) {
          bf16x8 ak[4];
#pragma unroll
          for (int mf = 0; mf < 4; ++mf)
            ak[mf] = *(const bf16x8*)(kl + (mf * 16 + ln) * 256 + ((kk * 64 + g * 16) ^ ((ln & 7) << 4)));
#pragma unroll
          for (int mf = 0; mf < 4; ++mf) {
            st[0][mf] = __builtin_amdgcn_mfma_f32_16x16x32_bf16(ak[mf], bq[0][kk], st[0][mf], 0, 0, 0);
            st[1][mf] = __builtin_amdgcn_mfma_f32_16x16x32_bf16(ak[mf], bq[1][kk], st[1][mf], 0, 0, 0);
          }
        }
        __builtin_amdgcn_s_setprio(0);

        // causal mask: slot (mf,g,r) holds TRUE kv = kv0 + 32(mf>>1) + 8g + 4(mf&1) + r
        if (kv0 + 63 > qw) {
#pragma unroll
          for (int f = 0; f < 2; ++f)
#pragma unroll
            for (int mf = 0; mf < 4; ++mf)
#pragma unroll
              for (int r = 0; r < 4; ++r)
                if (kv0 + 32 * (mf >> 1) + 8 * g + 4 * (mf & 1) + r > qw + f * 16 + ln)
                  st[f][mf][r] = -INFINITY;
        }

        bf16x8 ap[2][2]; // [f][ks]
#pragma unroll
        for (int f = 0; f < 2; ++f) {
          float pmax = -INFINITY;
#pragma unroll
          for (int mf = 0; mf < 4; ++mf)
#pragma unroll
            for (int r = 0; r < 4; ++r) pmax = fmaxf(pmax, st[f][mf][r]);
          pmax = fmaxf(pmax, __shfl_xor(pmax, 16));
          pmax = fmaxf(pmax, __shfl_xor(pmax, 32));
          float msub = mrun[f];
          if (__any(pmax > mrun[f] + 8.f)) { // defer-max
            msub = fmaxf(mrun[f], pmax);
            float fac = __builtin_amdgcn_exp2f(mrun[f] - msub);
            mrun[f] = msub;
            lrun[f] *= fac;
            float fr[4];
#pragma unroll
            for (int r = 0; r < 4; ++r) fr[r] = __shfl(fac, g * 4 + r);
#pragma unroll
            for (int nf = 0; nf < 8; ++nf) {
              acc[f][nf][0] *= fr[0]; acc[f][nf][1] *= fr[1];
              acc[f][nf][2] *= fr[2]; acc[f][nf][3] *= fr[3];
            }
          }
          uint32_t Aq[4][2];
          float psum = 0.f;
#pragma unroll
          for (int mf = 0; mf < 4; ++mf) {
            float p0 = __builtin_amdgcn_exp2f(st[f][mf][0] - msub);
            float p1 = __builtin_amdgcn_exp2f(st[f][mf][1] - msub);
            float p2 = __builtin_amdgcn_exp2f(st[f][mf][2] - msub);
            float p3 = __builtin_amdgcn_exp2f(st[f][mf][3] - msub);
            psum += (p0 + p1) + (p2 + p3);
            asm("v_cvt_pk_bf16_f32 %0, %1, %2" : "=v"(Aq[mf][0]) : "v"(p0), "v"(p1));
            asm("v_cvt_pk_bf16_f32 %0, %1, %2" : "=v"(Aq[mf][1]) : "v"(p2), "v"(p3));
          }
          psum += __shfl_xor(psum, 16);
          psum += __shfl_xor(psum, 32);
          lrun[f] += psum;

          // shuffle-free routing (K-row permutation): ap[ks] = {Aq[2ks], Aq[2ks+1]}
#pragma unroll
          for (int ks = 0; ks < 2; ++ks) {
            union { uint32_t u[4]; bf16x8 v; } t;
            t.u[0] = Aq[2 * ks][0];     t.u[1] = Aq[2 * ks][1];
            t.u[2] = Aq[2 * ks + 1][0]; t.u[3] = Aq[2 * ks + 1][1];
            ap[f][ks] = t.v;
          }
        }

        __builtin_amdgcn_s_setprio(1);
#pragma unroll
        for (int nf = 0; nf < 8; ++nf) {
          int d = nf * 16 + ln;
#pragma unroll
          for (int ks = 0; ks < 2; ++ks) {
            bf16x8 bv = *(const bf16x8*)(vl + d * 128 + ((ks * 64 + g * 16) ^ ((ln & 7) << 4)));
            acc[0][nf] = __builtin_amdgcn_mfma_f32_16x16x32_bf16(ap[0][ks], bv, acc[0][nf], 0, 0, 0);
            acc[1][nf] = __builtin_amdgcn_mfma_f32_16x16x32_bf16(ap[1][ks], bv, acc[1][nf], 0, 0, 0);
          }
        }
        __builtin_amdgcn_s_setprio(0);
      }
      __syncthreads();
      cur ^= 1;
    }

    // epilogue: divide by row sum, write ctx [B, T, NH*HD]
#pragma unroll
    for (int f = 0; f < 2; ++f) {
      float inv[4];
#pragma unroll
      for (int r = 0; r < 4; ++r) inv[r] = 1.f / __shfl(lrun[f], g * 4 + r);
#pragma unroll
      for (int nf = 0; nf < 8; ++nf) {
#pragma unroll
        for (int r = 0; r < 4; ++r) {
          int qrow = qw + f * 16 + g * 4 + r;
          ctx[((size_t)(b * T_SEQ + qrow)) * H_DIM + h * HD_ + nf * 16 + ln] =
              f2b(acc[f][nf][r] * inv[r]);
        }
      }
    }
  }
#undef STAGE_KV
}

// ---------------- host launch ----------------
extern "C" void kernel_launch(void* const* d_in, const int* in_sizes, int n_in,
                              void* d_out, int out_size, void* d_ws, size_t ws_size,
                              hipStream_t stream) {
  (void)in_sizes; (void)n_in; (void)out_size; (void)ws_size;
  const float* x  = (const float*)d_in[0];
  const float* qw = (const float*)d_in[1];
  const float* qb = (const float*)d_in[2];
  const float* kw = (const float*)d_in[3];
  const float* kb = (const float*)d_in[4];
  const float* vw = (const float*)d_in[5];
  const float* vb = (const float*)d_in[6];
  const float* ow = (const float*)d_in[7];
  const float* ob = (const float*)d_in[8];

  char* ws = (char*)d_ws;
  unsigned short* xb  = (unsigned short*)(ws);              // 32 MiB (x bf16; later reused as ctx)
  unsigned short* qwb = (unsigned short*)(ws + 33554432);   // 8 MiB
  unsigned short* kwb = (unsigned short*)(ws + 41943040);
  unsigned short* vwb = (unsigned short*)(ws + 50331648);
  unsigned short* owb = (unsigned short*)(ws + 58720256);
  unsigned short* Qb  = (unsigned short*)(ws + 67108864);   // 32 MiB [B,NH,T,HD]
  unsigned short* Kb  = (unsigned short*)(ws + 100663296);  // 32 MiB (row-permuted per 64)
  unsigned short* Vtb = (unsigned short*)(ws + 134217728);  // 32 MiB [B,NH,HD,T]
  unsigned short* ctxb = xb;                                // alias: x dead after V proj

  const float cscale = 0.08838834764831845f * 1.4426950408889634f; // SCALE * log2(e)

  dim3 blk(256);
  cvt_bf16_k<<<2048, blk, 0, stream>>>(x, xb, (MTOK * H_DIM) / 4);
  cvt4_bf16_k<<<2048, blk, 0, stream>>>(qw, kw, vw, ow, qwb, kwb, vwb, owb);

  dim3 ggrid(H_DIM / 256, MTOK / 256); // (8, 32) = 256 blocks
  dim3 gblk(512);
  gemm256_k<0><<<ggrid, gblk, 0, stream>>>(xb, qwb, qb, Qb, cscale); // Q pre-scaled
  gemm256_k<3><<<ggrid, gblk, 0, stream>>>(xb, kwb, kb, Kb, 1.0f);   // K row-permuted
  gemm256_k<1><<<ggrid, gblk, 0, stream>>>(xb, vwb, vb, Vtb, 1.0f);

  attn128_k<<<dim3(512), dim3(256), 0, stream>>>(Qb, Kb, Vtb, ctxb);

  gemm256_k<2><<<ggrid, gblk, 0, stream>>>(ctxb, owb, ob, (float*)d_out, 1.0f);
}

// Round 20
// 373.786 us; speedup vs baseline: 1.3220x; 1.0187x over previous
//
#include <hip/hip_runtime.h>
#include <stdint.h>

// Problem constants
#define B_SZ 4
#define T_SEQ 2048
#define H_DIM 2048
#define NH_ 16
#define HD_ 128
#define MTOK (B_SZ * T_SEQ) // 8192

typedef __attribute__((ext_vector_type(8))) short bf16x8;
typedef __attribute__((ext_vector_type(4))) float f32x4;
typedef __attribute__((ext_vector_type(4))) unsigned short u16x4;

__device__ __forceinline__ unsigned short f2b(float f) {
  union { float f; uint32_t u; } x; x.f = f;
  uint32_t r = x.u + 0x7FFFu + ((x.u >> 16) & 1u); // RNE
  return (unsigned short)(r >> 16);
}

__device__ __forceinline__ void gload16(const void* g, void* l) {
  // width-16 global->LDS DMA; LDS dest is wave-uniform base, HW scatters lane*16
  __builtin_amdgcn_global_load_lds((const __attribute__((address_space(1))) void*)g,
                                   (__attribute__((address_space(3))) void*)l, 16, 0, 0);
}

// ---------------- f32 -> bf16 conversion ----------------
__global__ void cvt_bf16_k(const float* __restrict__ in, unsigned short* __restrict__ out, int n4) {
  for (int i = blockIdx.x * blockDim.x + threadIdx.x; i < n4; i += gridDim.x * blockDim.x) {
    float4 v = ((const float4*)in)[i];
    u16x4 o;
    o[0] = f2b(v.x); o[1] = f2b(v.y); o[2] = f2b(v.z); o[3] = f2b(v.w);
    ((u16x4*)out)[i] = o;
  }
}

// 4 weight matrices (each 1M float4 groups) in one launch; buffer = idx >> 20.
__global__ void cvt4_bf16_k(const float* __restrict__ s0, const float* __restrict__ s1,
                            const float* __restrict__ s2, const float* __restrict__ s3,
                            unsigned short* __restrict__ d0, unsigned short* __restrict__ d1,
                            unsigned short* __restrict__ d2, unsigned short* __restrict__ d3) {
  const int n4each = (H_DIM * H_DIM) / 4; // 1M
  for (int i = blockIdx.x * blockDim.x + threadIdx.x; i < 4 * n4each; i += gridDim.x * blockDim.x) {
    int sel = i >> 20, j = i & (n4each - 1);
    const float* src = sel == 0 ? s0 : sel == 1 ? s1 : sel == 2 ? s2 : s3;
    unsigned short* dst = sel == 0 ? d0 : sel == 1 ? d1 : sel == 2 ? d2 : d3;
    float4 v = ((const float4*)src)[j];
    u16x4 o;
    o[0] = f2b(v.x); o[1] = f2b(v.y); o[2] = f2b(v.z); o[3] = f2b(v.w);
    ((u16x4*)dst)[j] = o;
  }
}

// ---------------- fused QKV GEMM: 768 blocks, sel = bid>>8 picks matrix ----------
// K-loop identical to the r12-verified gemm256_k. One launch instead of three:
// CUs finishing Q-blocks backfill with K/V blocks -> one dispatch tail, not three.
// sel 0: Q -> [B,NH,T,HD], pre-scaled by qscale
// sel 1: K -> [B,NH,T,HD] with intra-64 kv row permutation (shuffle-free attn routing)
// sel 2: V -> [B,NH,HD,T] transposed
__global__ __launch_bounds__(512, 2) void qkv_gemm_k(const unsigned short* __restrict__ xA,
                                                     const unsigned short* __restrict__ qwb,
                                                     const unsigned short* __restrict__ kwb,
                                                     const unsigned short* __restrict__ vwb,
                                                     const float* __restrict__ qb,
                                                     const float* __restrict__ kb,
                                                     const float* __restrict__ vb,
                                                     unsigned short* __restrict__ Qo,
                                                     unsigned short* __restrict__ Ko,
                                                     unsigned short* __restrict__ Vo,
                                                     float qscale) {
  constexpr int K = H_DIM;   // 2048
  constexpr int NT = K / 64; // 32 K-tiles
  __shared__ __align__(16) unsigned short Al[2][256 * 64];
  __shared__ __align__(16) unsigned short Bl[2][256 * 64];

  const int tid = threadIdx.x;
  const int w = tid >> 6, l = tid & 63;
  const int g = l >> 4, ln = l & 15;
  const int wr = w >> 2, wc = w & 3;

  const int bid0 = blockIdx.x;
  const int sel = bid0 >> 8;       // 0:Q 1:K 2:V (wave-uniform)
  const int bid = bid0 & 255;
  const int fid = ((bid & 7) << 5) | (bid >> 3);
  const int col0 = (fid & 7) * 256;
  const int row0 = (fid >> 3) * 256;

  const unsigned short* Wm = sel == 0 ? qwb : sel == 1 ? kwb : vwb;
  const float* bias = sel == 0 ? qb : sel == 1 ? kb : vb;

  const char* Ag = (const char*)xA;
  const char* Wg = (const char*)Wm;

  const int srow = l >> 3;
  const int sbyte = ((l & 7) * 16) ^ (srow << 4);

#define ST_A(t2, b2, c)                                                                 \
  gload16(Ag + (((size_t)(row0 + (c) * 8 + srow)) * K + (t2) * 64) * 2 + sbyte,         \
          (char*)&Al[b2][0] + (c) * 1024)
#define ST_B(t2, b2, c)                                                                 \
  gload16(Wg + (((size_t)(col0 + (c) * 8 + srow)) * K + (t2) * 64) * 2 + sbyte,         \
          (char*)&Bl[b2][0] + (c) * 1024)
#define STAGE_A0(t2, b2) do { ST_A(t2, b2, w);  ST_A(t2, b2, 16 + w); } while (0)
#define STAGE_A1(t2, b2) do { ST_A(t2, b2, 8 + w); ST_A(t2, b2, 24 + w); } while (0)
#define STAGE_B0(t2, b2) do { int c_ = (w >> 2) * 8 + (w & 3); ST_B(t2, b2, c_); ST_B(t2, b2, 16 + c_); } while (0)
#define STAGE_B1(t2, b2) do { int c_ = (w >> 2) * 8 + 4 + (w & 3); ST_B(t2, b2, c_); ST_B(t2, b2, 16 + c_); } while (0)

  f32x4 acc[8][4] = {};
  bf16x8 aF[4][2];
  bf16x8 bF[2][2][2];

#define READ_A(mh)                                                                      \
  _Pragma("unroll") for (int mf = 0; mf < 4; ++mf)                                      \
  _Pragma("unroll") for (int ks = 0; ks < 2; ++ks) {                                    \
    int row_ = wr * 128 + (mh) * 64 + mf * 16 + ln;                                     \
    aF[mf][ks] = *(const bf16x8*)((const char*)Ab + row_ * 128 +                        \
                                  ((ks * 64 + g * 16) ^ ((ln & 7) << 4)));              \
  }
#define READ_B(nh)                                                                      \
  _Pragma("unroll") for (int nf = 0; nf < 2; ++nf)                                      \
  _Pragma("unroll") for (int ks = 0; ks < 2; ++ks) {                                    \
    int row_ = wc * 64 + (nh) * 32 + nf * 16 + ln;                                      \
    bF[nh][nf][ks] = *(const bf16x8*)((const char*)Bb + row_ * 128 +                    \
                                      ((ks * 64 + g * 16) ^ ((ln & 7) << 4)));          \
  }
#define MFMA_PHASE(mh, nh)                                                              \
  do {                                                                                  \
    __builtin_amdgcn_s_setprio(1);                                                      \
    _Pragma("unroll") for (int mf = 0; mf < 4; ++mf)                                    \
    _Pragma("unroll") for (int nf = 0; nf < 2; ++nf)                                    \
    _Pragma("unroll") for (int ks = 0; ks < 2; ++ks)                                    \
      acc[(mh) * 4 + mf][(nh) * 2 + nf] = __builtin_amdgcn_mfma_f32_16x16x32_bf16(      \
          aF[mf][ks], bF[nh][nf][ks], acc[(mh) * 4 + mf][(nh) * 2 + nf], 0, 0, 0);      \
    __builtin_amdgcn_s_setprio(0);                                                      \
  } while (0)
#define BARRIER() asm volatile("s_barrier" ::: "memory")

  STAGE_A0(0, 0); STAGE_B0(0, 0); STAGE_B1(0, 0); STAGE_A1(0, 0);
  STAGE_A0(1, 1); STAGE_B0(1, 1); STAGE_B1(1, 1); STAGE_A1(1, 1);
  asm volatile("s_waitcnt vmcnt(8)" ::: "memory");
  BARRIER();

#pragma unroll 1
  for (int t = 0; t < NT; ++t) {
    const int buf = t & 1;
    const unsigned short* Ab = &Al[buf][0];
    const unsigned short* Bb = &Bl[buf][0];
    READ_A(0); READ_B(0);
    if (t >= 1 && t + 1 < NT) STAGE_A1(t + 1, (t + 1) & 1);
    BARRIER();
    MFMA_PHASE(0, 0);
    BARRIER();
    READ_B(1);
    if (t + 2 < NT) STAGE_A0(t + 2, buf);
    BARRIER();
    MFMA_PHASE(0, 1);
    BARRIER();
    READ_A(1);
    if (t + 2 < NT) STAGE_B0(t + 2, buf);
    BARRIER();
    MFMA_PHASE(1, 0);
    BARRIER();
    if (t + 2 < NT) {
      STAGE_B1(t + 2, buf);
      asm volatile("s_waitcnt vmcnt(6)" ::: "memory");
    } else {
      asm volatile("s_waitcnt vmcnt(0)" ::: "memory");
    }
    BARRIER();
    MFMA_PHASE(1, 1);
    BARRIER();
  }

  // ---- epilogue (uniform branch on sel) ----
  if (sel == 0) { // Q: [B,NH,T,HD], pre-scaled
    unsigned short* out = Qo;
#pragma unroll
    for (int mi = 0; mi < 8; ++mi)
#pragma unroll
      for (int ni = 0; ni < 4; ++ni) {
        int n = col0 + wc * 64 + ni * 16 + ln;
        float bv = bias[n];
        int h = n >> 7, d = n & 127;
#pragma unroll
        for (int r = 0; r < 4; ++r) {
          int m = row0 + wr * 128 + mi * 16 + 4 * g + r;
          int b = m >> 11, tt = m & 2047;
          out[(((size_t)(b * NH_ + h)) * T_SEQ + tt) * HD_ + d] = f2b((acc[mi][ni][r] + bv) * qscale);
        }
      }
  } else if (sel == 1) { // K: [B,NH,T,HD] + intra-64 row permutation
    unsigned short* out = Ko;
#pragma unroll
    for (int mi = 0; mi < 8; ++mi)
#pragma unroll
      for (int ni = 0; ni < 4; ++ni) {
        int n = col0 + wc * 64 + ni * 16 + ln;
        float bv = bias[n];
        int h = n >> 7, d = n & 127;
#pragma unroll
        for (int r = 0; r < 4; ++r) {
          int m = row0 + wr * 128 + mi * 16 + 4 * g + r;
          int b = m >> 11, tt = m & 2047;
          int tl = tt & 63;
          int tp = (tt & ~63) | ((tl >> 5) * 32 + ((tl >> 2) & 1) * 16 + ((tl >> 3) & 3) * 4 + (tl & 3));
          out[(((size_t)(b * NH_ + h)) * T_SEQ + tp) * HD_ + d] = f2b(acc[mi][ni][r] + bv);
        }
      }
  } else { // V: transposed [B,NH,HD,T]
    unsigned short* out = Vo;
#pragma unroll
    for (int mi = 0; mi < 8; ++mi)
#pragma unroll
      for (int ni = 0; ni < 4; ++ni) {
        int n = col0 + wc * 64 + ni * 16 + ln;
        float bv = bias[n];
        int h = n >> 7, d = n & 127;
        int m0 = row0 + wr * 128 + mi * 16 + 4 * g;
        int b = m0 >> 11, t0 = m0 & 2047;
        u16x4 pk;
#pragma unroll
        for (int r = 0; r < 4; ++r) pk[r] = f2b(acc[mi][ni][r] + bv);
        *(u16x4*)&out[(((size_t)(b * NH_ + h)) * HD_ + d) * T_SEQ + t0] = pk;
      }
  }
#undef ST_A
#undef ST_B
#undef STAGE_A0
#undef STAGE_A1
#undef STAGE_B0
#undef STAGE_B1
#undef READ_A
#undef READ_B
#undef MFMA_PHASE
#undef BARRIER
}

// ---------------- output-projection GEMM (r12-verified, f32 out) ----------
__global__ __launch_bounds__(512, 2) void gemm_out_k(const unsigned short* __restrict__ A,
                                                     const unsigned short* __restrict__ W,
                                                     const float* __restrict__ bias,
                                                     float* __restrict__ outp) {
  constexpr int K = H_DIM;   // 2048
  constexpr int NT = K / 64; // 32 K-tiles
  __shared__ __align__(16) unsigned short Al[2][256 * 64];
  __shared__ __align__(16) unsigned short Bl[2][256 * 64];

  const int tid = threadIdx.x;
  const int w = tid >> 6, l = tid & 63;
  const int g = l >> 4, ln = l & 15;
  const int wr = w >> 2, wc = w & 3;

  const int bid = blockIdx.x + gridDim.x * blockIdx.y;
  const int fid = ((bid & 7) << 5) | (bid >> 3);
  const int col0 = (fid & 7) * 256;
  const int row0 = (fid >> 3) * 256;

  const char* Ag = (const char*)A;
  const char* Wg = (const char*)W;

  const int srow = l >> 3;
  const int sbyte = ((l & 7) * 16) ^ (srow << 4);

#define ST_A(t2, b2, c)                                                                 \
  gload16(Ag + (((size_t)(row0 + (c) * 8 + srow)) * K + (t2) * 64) * 2 + sbyte,         \
          (char*)&Al[b2][0] + (c) * 1024)
#define ST_B(t2, b2, c)                                                                 \
  gload16(Wg + (((size_t)(col0 + (c) * 8 + srow)) * K + (t2) * 64) * 2 + sbyte,         \
          (char*)&Bl[b2][0] + (c) * 1024)
#define STAGE_A0(t2, b2) do { ST_A(t2, b2, w);  ST_A(t2, b2, 16 + w); } while (0)
#define STAGE_A1(t2, b2) do { ST_A(t2, b2, 8 + w); ST_A(t2, b2, 24 + w); } while (0)
#define STAGE_B0(t2, b2) do { int c_ = (w >> 2) * 8 + (w & 3); ST_B(t2, b2, c_); ST_B(t2, b2, 16 + c_); } while (0)
#define STAGE_B1(t2, b2) do { int c_ = (w >> 2) * 8 + 4 + (w & 3); ST_B(t2, b2, c_); ST_B(t2, b2, 16 + c_); } while (0)

  f32x4 acc[8][4] = {};
  bf16x8 aF[4][2];
  bf16x8 bF[2][2][2];

#define READ_A(mh)                                                                      \
  _Pragma("unroll") for (int mf = 0; mf < 4; ++mf)                                      \
  _Pragma("unroll") for (int ks = 0; ks < 2; ++ks) {                                    \
    int row_ = wr * 128 + (mh) * 64 + mf * 16 + ln;                                     \
    aF[mf][ks] = *(const bf16x8*)((const char*)Ab + row_ * 128 +                        \
                                  ((ks * 64 + g * 16) ^ ((ln & 7) << 4)));              \
  }
#define READ_B(nh)                                                                      \
  _Pragma("unroll") for (int nf = 0; nf < 2; ++nf)                                      \
  _Pragma("unroll") for (int ks = 0; ks < 2; ++ks) {                                    \
    int row_ = wc * 64 + (nh) * 32 + nf * 16 + ln;                                      \
    bF[nh][nf][ks] = *(const bf16x8*)((const char*)Bb + row_ * 128 +                    \
                                      ((ks * 64 + g * 16) ^ ((ln & 7) << 4)));          \
  }
#define MFMA_PHASE(mh, nh)                                                              \
  do {                                                                                  \
    __builtin_amdgcn_s_setprio(1);                                                      \
    _Pragma("unroll") for (int mf = 0; mf < 4; ++mf)                                    \
    _Pragma("unroll") for (int nf = 0; nf < 2; ++nf)                                    \
    _Pragma("unroll") for (int ks = 0; ks < 2; ++ks)                                    \
      acc[(mh) * 4 + mf][(nh) * 2 + nf] = __builtin_amdgcn_mfma_f32_16x16x32_bf16(      \
          aF[mf][ks], bF[nh][nf][ks], acc[(mh) * 4 + mf][(nh) * 2 + nf], 0, 0, 0);      \
    __builtin_amdgcn_s_setprio(0);                                                      \
  } while (0)
#define BARRIER() asm volatile("s_barrier" ::: "memory")

  STAGE_A0(0, 0); STAGE_B0(0, 0); STAGE_B1(0, 0); STAGE_A1(0, 0);
  STAGE_A0(1, 1); STAGE_B0(1, 1); STAGE_B1(1, 1); STAGE_A1(1, 1);
  asm volatile("s_waitcnt vmcnt(8)" ::: "memory");
  BARRIER();

#pragma unroll 1
  for (int t = 0; t < NT; ++t) {
    const int buf = t & 1;
    const unsigned short* Ab = &Al[buf][0];
    const unsigned short* Bb = &Bl[buf][0];
    READ_A(0); READ_B(0);
    if (t >= 1 && t + 1 < NT) STAGE_A1(t + 1, (t + 1) & 1);
    BARRIER();
    MFMA_PHASE(0, 0);
    BARRIER();
    READ_B(1);
    if (t + 2 < NT) STAGE_A0(t + 2, buf);
    BARRIER();
    MFMA_PHASE(0, 1);
    BARRIER();
    READ_A(1);
    if (t + 2 < NT) STAGE_B0(t + 2, buf);
    BARRIER();
    MFMA_PHASE(1, 0);
    BARRIER();
    if (t + 2 < NT) {
      STAGE_B1(t + 2, buf);
      asm volatile("s_waitcnt vmcnt(6)" ::: "memory");
    } else {
      asm volatile("s_waitcnt vmcnt(0)" ::: "memory");
    }
    BARRIER();
    MFMA_PHASE(1, 1);
    BARRIER();
  }

#pragma unroll
  for (int mi = 0; mi < 8; ++mi)
#pragma unroll
    for (int ni = 0; ni < 4; ++ni) {
      int n = col0 + wc * 64 + ni * 16 + ln;
      float bv = bias[n];
#pragma unroll
      for (int r = 0; r < 4; ++r) {
        int m = row0 + wr * 128 + mi * 16 + 4 * g + r;
        outp[(size_t)m * H_DIM + n] = acc[mi][ni][r] + bv;
      }
    }
#undef ST_A
#undef ST_B
#undef STAGE_A0
#undef STAGE_A1
#undef STAGE_B0
#undef STAGE_B1
#undef READ_A
#undef READ_B
#undef MFMA_PHASE
#undef BARRIER
}

// ---------------- causal flash attention (r16-verified, ~104 us) ----------------
// QBLK=128 (4 waves), 512 blocks, serial q-tile pair (15-pr, pr) -> 34 iters each;
// 2 blocks/CU. K rows pre-permuted -> shuffle-free P routing; in-reg P.
__global__ __launch_bounds__(256, 2) void attn128_k(const unsigned short* __restrict__ Q,
                                                    const unsigned short* __restrict__ Kg,
                                                    const unsigned short* __restrict__ Vt,
                                                    unsigned short* __restrict__ ctx) {
  __shared__ __align__(16) unsigned short Kl[2][64 * 128]; // [kv-slot][k] swizzled rows (256B)
  __shared__ __align__(16) unsigned short Vl[2][128 * 64]; // [d][kv] swizzled rows (128B)

  const int tid = threadIdx.x;
  const int w = tid >> 6, l = tid & 63;   // w: 0..3
  const int g = l >> 4, ln = l & 15;

  // XCD grouping: 512 blocks -> 64 consecutive per XCD; each bh's 8 blocks on one XCD
  const int flat = ((blockIdx.x & 7) << 6) | (blockIdx.x >> 3);
  const int bh = flat >> 3;  // 0..63
  const int pr = flat & 7;   // 0..7 -> q-tile pair (15-pr, pr)

  const char* kbase = (const char*)(Kg + (size_t)bh * T_SEQ * HD_);
  const char* vbase = (const char*)(Vt + (size_t)bh * HD_ * T_SEQ);
  const int b = bh >> 4, h = bh & 15;

#define STAGE_KV(bufi, ktile) do {                                                    \
    int kv0_ = (ktile) * 64;                                                          \
    _Pragma("unroll")                                                                 \
    for (int i_ = 0; i_ < 4; ++i_) {                                                  \
      int c_ = w * 4 + i_;                                                            \
      int kvr_ = c_ * 4 + g;                                                          \
      gload16(kbase + ((size_t)(kv0_ + kvr_) * HD_) * 2 + ((ln * 16) ^ ((kvr_ & 7) << 4)), \
              (char*)&Kl[bufi][0] + c_ * 1024);                                       \
      int d_ = c_ * 8 + (l >> 3);                                                     \
      gload16(vbase + ((size_t)d_ * T_SEQ + kv0_) * 2 + (((l & 7) * 16) ^ ((d_ & 7) << 4)), \
              (char*)&Vl[bufi][0] + c_ * 1024);                                       \
    } } while (0)

#pragma unroll 1
  for (int half = 0; half < 2; ++half) {
    const int qt = half ? pr : (15 - pr); // heavy 128-row tile first
    const int q0 = qt << 7;
    const int qw = q0 + w * 32;           // wave's first q row

    bf16x8 bq[2][4];
#pragma unroll
    for (int f = 0; f < 2; ++f)
#pragma unroll
      for (int kk = 0; kk < 4; ++kk)
        bq[f][kk] = *(const bf16x8*)(Q + ((size_t)bh * T_SEQ + qw + f * 16 + ln) * HD_ + kk * 32 + g * 8);

    f32x4 acc[2][8] = {};
    float mrun[2] = {-INFINITY, -INFINITY};
    float lrun[2] = {0.f, 0.f};

    const int nt = (qt + 1) * 2;

    STAGE_KV(0, 0);
    __syncthreads();
    int cur = 0;

#pragma unroll 1
    for (int kt = 0; kt < nt; ++kt) {
      if (kt + 1 < nt) STAGE_KV(cur ^ 1, kt + 1); // prefetch overlaps compute
      const int kv0 = kt * 64;
      if (kv0 <= qw + 31) { // causal wave-skip (barriers stay outside)
        const char* kl = (const char*)&Kl[cur][0];
        const char* vl = (const char*)&Vl[cur][0];

        // S^T[kv-slot][q] = K . Q^T
        f32x4 st[2][4] = {};
        __builtin_amdgcn_s_setprio(1);
#pragma unroll
        for (int kk = 0; kk < 4; ++kk) {
          bf16x8 ak[4];
#pragma unroll
          for (int mf = 0; mf < 4; ++mf)
            ak[mf] = *(const bf16x8*)(kl + (mf * 16 + ln) * 256 + ((kk * 64 + g * 16) ^ ((ln & 7) << 4)));
#pragma unroll
          for (int mf = 0; mf < 4; ++mf) {
            st[0][mf] = __builtin_amdgcn_mfma_f32_16x16x32_bf16(ak[mf], bq[0][kk], st[0][mf], 0, 0, 0);
            st[1][mf] = __builtin_amdgcn_mfma_f32_16x16x32_bf16(ak[mf], bq[1][kk], st[1][mf], 0, 0, 0);
          }
        }
        __builtin_amdgcn_s_setprio(0);

        // causal mask: slot (mf,g,r) holds TRUE kv = kv0 + 32(mf>>1) + 8g + 4(mf&1) + r
        if (kv0 + 63 > qw) {
#pragma unroll
          for (int f = 0; f < 2; ++f)
#pragma unroll
            for (int mf = 0; mf < 4; ++mf)
#pragma unroll
              for (int r = 0; r < 4; ++r)
                if (kv0 + 32 * (mf >> 1) + 8 * g + 4 * (mf & 1) + r > qw + f * 16 + ln)
                  st[f][mf][r] = -INFINITY;
        }

        bf16x8 ap[2][2]; // [f][ks]
#pragma unroll
        for (int f = 0; f < 2; ++f) {
          float pmax = -INFINITY;
#pragma unroll
          for (int mf = 0; mf < 4; ++mf)
#pragma unroll
            for (int r = 0; r < 4; ++r) pmax = fmaxf(pmax, st[f][mf][r]);
          pmax = fmaxf(pmax, __shfl_xor(pmax, 16));
          pmax = fmaxf(pmax, __shfl_xor(pmax, 32));
          float msub = mrun[f];
          if (__any(pmax > mrun[f] + 8.f)) { // defer-max
            msub = fmaxf(mrun[f], pmax);
            float fac = __builtin_amdgcn_exp2f(mrun[f] - msub);
            mrun[f] = msub;
            lrun[f] *= fac;
            float fr[4];
#pragma unroll
            for (int r = 0; r < 4; ++r) fr[r] = __shfl(fac, g * 4 + r);
#pragma unroll
            for (int nf = 0; nf < 8; ++nf) {
              acc[f][nf][0] *= fr[0]; acc[f][nf][1] *= fr[1];
              acc[f][nf][2] *= fr[2]; acc[f][nf][3] *= fr[3];
            }
          }
          uint32_t Aq[4][2];
          float psum = 0.f;
#pragma unroll
          for (int mf = 0; mf < 4; ++mf) {
            float p0 = __builtin_amdgcn_exp2f(st[f][mf][0] - msub);
            float p1 = __builtin_amdgcn_exp2f(st[f][mf][1] - msub);
            float p2 = __builtin_amdgcn_exp2f(st[f][mf][2] - msub);
            float p3 = __builtin_amdgcn_exp2f(st[f][mf][3] - msub);
            psum += (p0 + p1) + (p2 + p3);
            asm("v_cvt_pk_bf16_f32 %0, %1, %2" : "=v"(Aq[mf][0]) : "v"(p0), "v"(p1));
            asm("v_cvt_pk_bf16_f32 %0, %1, %2" : "=v"(Aq[mf][1]) : "v"(p2), "v"(p3));
          }
          psum += __shfl_xor(psum, 16);
          psum += __shfl_xor(psum, 32);
          lrun[f] += psum;

          // shuffle-free routing (K-row permutation): ap[ks] = {Aq[2ks], Aq[2ks+1]}
#pragma unroll
          for (int ks = 0; ks < 2; ++ks) {
            union { uint32_t u[4]; bf16x8 v; } t;
            t.u[0] = Aq[2 * ks][0];     t.u[1] = Aq[2 * ks][1];
            t.u[2] = Aq[2 * ks + 1][0]; t.u[3] = Aq[2 * ks + 1][1];
            ap[f][ks] = t.v;
          }
        }

        __builtin_amdgcn_s_setprio(1);
#pragma unroll
        for (int nf = 0; nf < 8; ++nf) {
          int d = nf * 16 + ln;
#pragma unroll
          for (int ks = 0; ks < 2; ++ks) {
            bf16x8 bv = *(const bf16x8*)(vl + d * 128 + ((ks * 64 + g * 16) ^ ((ln & 7) << 4)));
            acc[0][nf] = __builtin_amdgcn_mfma_f32_16x16x32_bf16(ap[0][ks], bv, acc[0][nf], 0, 0, 0);
            acc[1][nf] = __builtin_amdgcn_mfma_f32_16x16x32_bf16(ap[1][ks], bv, acc[1][nf], 0, 0, 0);
          }
        }
        __builtin_amdgcn_s_setprio(0);
      }
      __syncthreads();
      cur ^= 1;
    }

    // epilogue: divide by row sum, write ctx [B, T, NH*HD]
#pragma unroll
    for (int f = 0; f < 2; ++f) {
      float inv[4];
#pragma unroll
      for (int r = 0; r < 4; ++r) inv[r] = 1.f / __shfl(lrun[f], g * 4 + r);
#pragma unroll
      for (int nf = 0; nf < 8; ++nf) {
#pragma unroll
        for (int r = 0; r < 4; ++r) {
          int qrow = qw + f * 16 + g * 4 + r;
          ctx[((size_t)(b * T_SEQ + qrow)) * H_DIM + h * HD_ + nf * 16 + ln] =
              f2b(acc[f][nf][r] * inv[r]);
        }
      }
    }
  }
#undef STAGE_KV
}

// ---------------- host launch ----------------
extern "C" void kernel_launch(void* const* d_in, const int* in_sizes, int n_in,
                              void* d_out, int out_size, void* d_ws, size_t ws_size,
                              hipStream_t stream) {
  (void)in_sizes; (void)n_in; (void)out_size; (void)ws_size;
  const float* x  = (const float*)d_in[0];
  const float* qw = (const float*)d_in[1];
  const float* qb = (const float*)d_in[2];
  const float* kw = (const float*)d_in[3];
  const float* kb = (const float*)d_in[4];
  const float* vw = (const float*)d_in[5];
  const float* vb = (const float*)d_in[6];
  const float* ow = (const float*)d_in[7];
  const float* ob = (const float*)d_in[8];

  char* ws = (char*)d_ws;
  unsigned short* xb  = (unsigned short*)(ws);              // 32 MiB (x bf16; later reused as ctx)
  unsigned short* qwb = (unsigned short*)(ws + 33554432);   // 8 MiB
  unsigned short* kwb = (unsigned short*)(ws + 41943040);
  unsigned short* vwb = (unsigned short*)(ws + 50331648);
  unsigned short* owb = (unsigned short*)(ws + 58720256);
  unsigned short* Qb  = (unsigned short*)(ws + 67108864);   // 32 MiB [B,NH,T,HD]
  unsigned short* Kb  = (unsigned short*)(ws + 100663296);  // 32 MiB (row-permuted per 64)
  unsigned short* Vtb = (unsigned short*)(ws + 134217728);  // 32 MiB [B,NH,HD,T]
  unsigned short* ctxb = xb;                                // alias: x dead after V proj

  const float cscale = 0.08838834764831845f * 1.4426950408889634f; // SCALE * log2(e)

  dim3 blk(256);
  cvt_bf16_k<<<2048, blk, 0, stream>>>(x, xb, (MTOK * H_DIM) / 4);
  cvt4_bf16_k<<<2048, blk, 0, stream>>>(qw, kw, vw, ow, qwb, kwb, vwb, owb);

  // fused Q/K/V projections: one 768-block launch (one dispatch tail, not three)
  qkv_gemm_k<<<dim3(768), dim3(512), 0, stream>>>(xb, qwb, kwb, vwb, qb, kb, vb,
                                                  Qb, Kb, Vtb, cscale);

  attn128_k<<<dim3(512), dim3(256), 0, stream>>>(Qb, Kb, Vtb, ctxb);

  gemm_out_k<<<dim3(8, 32), dim3(512), 0, stream>>>(ctxb, owb, ob, (float*)d_out);
}

// Round 21
// 372.157 us; speedup vs baseline: 1.3278x; 1.0044x over previous
//
#include <hip/hip_runtime.h>
#include <stdint.h>

// Problem constants
#define B_SZ 4
#define T_SEQ 2048
#define H_DIM 2048
#define NH_ 16
#define HD_ 128
#define MTOK (B_SZ * T_SEQ) // 8192

typedef __attribute__((ext_vector_type(8))) short bf16x8;
typedef __attribute__((ext_vector_type(4))) float f32x4;
typedef __attribute__((ext_vector_type(4))) unsigned short u16x4;

__device__ __forceinline__ unsigned short f2b(float f) {
  union { float f; uint32_t u; } x; x.f = f;
  uint32_t r = x.u + 0x7FFFu + ((x.u >> 16) & 1u); // RNE
  return (unsigned short)(r >> 16);
}

__device__ __forceinline__ void gload16(const void* g, void* l) {
  // width-16 global->LDS DMA; LDS dest is wave-uniform base, HW scatters lane*16
  __builtin_amdgcn_global_load_lds((const __attribute__((address_space(1))) void*)g,
                                   (__attribute__((address_space(3))) void*)l, 16, 0, 0);
}

// ---------------- f32 -> bf16 conversion: x + 4 weights in ONE launch ----------------
// 8M float4 groups total: i < 4M -> x; else weight sel = (i-4M)>>20 (1M each).
__global__ void cvt_all_k(const float* __restrict__ x,
                          const float* __restrict__ s0, const float* __restrict__ s1,
                          const float* __restrict__ s2, const float* __restrict__ s3,
                          unsigned short* __restrict__ xd,
                          unsigned short* __restrict__ d0, unsigned short* __restrict__ d1,
                          unsigned short* __restrict__ d2, unsigned short* __restrict__ d3) {
  const int nx4 = (MTOK * H_DIM) / 4;     // 4M
  const int nw4 = (H_DIM * H_DIM) / 4;    // 1M
  const int ntot = nx4 + 4 * nw4;         // 8M
  for (int i = blockIdx.x * blockDim.x + threadIdx.x; i < ntot; i += gridDim.x * blockDim.x) {
    const float* src;
    unsigned short* dst;
    int j;
    if (i < nx4) {
      src = x; dst = xd; j = i;
    } else {
      int k = i - nx4;
      int sel = k >> 20; j = k & (nw4 - 1);
      src = sel == 0 ? s0 : sel == 1 ? s1 : sel == 2 ? s2 : s3;
      dst = sel == 0 ? d0 : sel == 1 ? d1 : sel == 2 ? d2 : d3;
    }
    float4 v = ((const float4*)src)[j];
    u16x4 o;
    o[0] = f2b(v.x); o[1] = f2b(v.y); o[2] = f2b(v.z); o[3] = f2b(v.w);
    ((u16x4*)dst)[j] = o;
  }
}

// ---------------- fused QKV GEMM: 768 blocks, sel = bid>>8 picks matrix ----------
// K-loop identical to the r12-verified gemm256_k. One launch instead of three.
// sel 0: Q -> [B,NH,T,HD], pre-scaled by qscale
// sel 1: K -> [B,NH,T,HD] with intra-64 kv row permutation (shuffle-free attn routing)
// sel 2: V -> [B,NH,HD,T] transposed
__global__ __launch_bounds__(512, 2) void qkv_gemm_k(const unsigned short* __restrict__ xA,
                                                     const unsigned short* __restrict__ qwb,
                                                     const unsigned short* __restrict__ kwb,
                                                     const unsigned short* __restrict__ vwb,
                                                     const float* __restrict__ qb,
                                                     const float* __restrict__ kb,
                                                     const float* __restrict__ vb,
                                                     unsigned short* __restrict__ Qo,
                                                     unsigned short* __restrict__ Ko,
                                                     unsigned short* __restrict__ Vo,
                                                     float qscale) {
  constexpr int K = H_DIM;   // 2048
  constexpr int NT = K / 64; // 32 K-tiles
  __shared__ __align__(16) unsigned short Al[2][256 * 64];
  __shared__ __align__(16) unsigned short Bl[2][256 * 64];

  const int tid = threadIdx.x;
  const int w = tid >> 6, l = tid & 63;
  const int g = l >> 4, ln = l & 15;
  const int wr = w >> 2, wc = w & 3;

  const int bid0 = blockIdx.x;
  const int sel = bid0 >> 8;       // 0:Q 1:K 2:V (wave-uniform)
  const int bid = bid0 & 255;
  const int fid = ((bid & 7) << 5) | (bid >> 3);
  const int col0 = (fid & 7) * 256;
  const int row0 = (fid >> 3) * 256;

  const unsigned short* Wm = sel == 0 ? qwb : sel == 1 ? kwb : vwb;
  const float* bias = sel == 0 ? qb : sel == 1 ? kb : vb;

  const char* Ag = (const char*)xA;
  const char* Wg = (const char*)Wm;

  const int srow = l >> 3;
  const int sbyte = ((l & 7) * 16) ^ (srow << 4);

#define ST_A(t2, b2, c)                                                                 \
  gload16(Ag + (((size_t)(row0 + (c) * 8 + srow)) * K + (t2) * 64) * 2 + sbyte,         \
          (char*)&Al[b2][0] + (c) * 1024)
#define ST_B(t2, b2, c)                                                                 \
  gload16(Wg + (((size_t)(col0 + (c) * 8 + srow)) * K + (t2) * 64) * 2 + sbyte,         \
          (char*)&Bl[b2][0] + (c) * 1024)
#define STAGE_A0(t2, b2) do { ST_A(t2, b2, w);  ST_A(t2, b2, 16 + w); } while (0)
#define STAGE_A1(t2, b2) do { ST_A(t2, b2, 8 + w); ST_A(t2, b2, 24 + w); } while (0)
#define STAGE_B0(t2, b2) do { int c_ = (w >> 2) * 8 + (w & 3); ST_B(t2, b2, c_); ST_B(t2, b2, 16 + c_); } while (0)
#define STAGE_B1(t2, b2) do { int c_ = (w >> 2) * 8 + 4 + (w & 3); ST_B(t2, b2, c_); ST_B(t2, b2, 16 + c_); } while (0)

  f32x4 acc[8][4] = {};
  bf16x8 aF[4][2];
  bf16x8 bF[2][2][2];

#define READ_A(mh)                                                                      \
  _Pragma("unroll") for (int mf = 0; mf < 4; ++mf)                                      \
  _Pragma("unroll") for (int ks = 0; ks < 2; ++ks) {                                    \
    int row_ = wr * 128 + (mh) * 64 + mf * 16 + ln;                                     \
    aF[mf][ks] = *(const bf16x8*)((const char*)Ab + row_ * 128 +                        \
                                  ((ks * 64 + g * 16) ^ ((ln & 7) << 4)));              \
  }
#define READ_B(nh)                                                                      \
  _Pragma("unroll") for (int nf = 0; nf < 2; ++nf)                                      \
  _Pragma("unroll") for (int ks = 0; ks < 2; ++ks) {                                    \
    int row_ = wc * 64 + (nh) * 32 + nf * 16 + ln;                                      \
    bF[nh][nf][ks] = *(const bf16x8*)((const char*)Bb + row_ * 128 +                    \
                                      ((ks * 64 + g * 16) ^ ((ln & 7) << 4)));          \
  }
#define MFMA_PHASE(mh, nh)                                                              \
  do {                                                                                  \
    __builtin_amdgcn_s_setprio(1);                                                      \
    _Pragma("unroll") for (int mf = 0; mf < 4; ++mf)                                    \
    _Pragma("unroll") for (int nf = 0; nf < 2; ++nf)                                    \
    _Pragma("unroll") for (int ks = 0; ks < 2; ++ks)                                    \
      acc[(mh) * 4 + mf][(nh) * 2 + nf] = __builtin_amdgcn_mfma_f32_16x16x32_bf16(      \
          aF[mf][ks], bF[nh][nf][ks], acc[(mh) * 4 + mf][(nh) * 2 + nf], 0, 0, 0);      \
    __builtin_amdgcn_s_setprio(0);                                                      \
  } while (0)
#define BARRIER() asm volatile("s_barrier" ::: "memory")

  STAGE_A0(0, 0); STAGE_B0(0, 0); STAGE_B1(0, 0); STAGE_A1(0, 0);
  STAGE_A0(1, 1); STAGE_B0(1, 1); STAGE_B1(1, 1); STAGE_A1(1, 1);
  asm volatile("s_waitcnt vmcnt(8)" ::: "memory");
  BARRIER();

#pragma unroll 1
  for (int t = 0; t < NT; ++t) {
    const int buf = t & 1;
    const unsigned short* Ab = &Al[buf][0];
    const unsigned short* Bb = &Bl[buf][0];
    READ_A(0); READ_B(0);
    if (t >= 1 && t + 1 < NT) STAGE_A1(t + 1, (t + 1) & 1);
    BARRIER();
    MFMA_PHASE(0, 0);
    BARRIER();
    READ_B(1);
    if (t + 2 < NT) STAGE_A0(t + 2, buf);
    BARRIER();
    MFMA_PHASE(0, 1);
    BARRIER();
    READ_A(1);
    if (t + 2 < NT) STAGE_B0(t + 2, buf);
    BARRIER();
    MFMA_PHASE(1, 0);
    BARRIER();
    if (t + 2 < NT) {
      STAGE_B1(t + 2, buf);
      asm volatile("s_waitcnt vmcnt(6)" ::: "memory");
    } else {
      asm volatile("s_waitcnt vmcnt(0)" ::: "memory");
    }
    BARRIER();
    MFMA_PHASE(1, 1);
    BARRIER();
  }

  // ---- epilogue (uniform branch on sel) ----
  if (sel == 0) { // Q: [B,NH,T,HD], pre-scaled
    unsigned short* out = Qo;
#pragma unroll
    for (int mi = 0; mi < 8; ++mi)
#pragma unroll
      for (int ni = 0; ni < 4; ++ni) {
        int n = col0 + wc * 64 + ni * 16 + ln;
        float bv = bias[n];
        int h = n >> 7, d = n & 127;
#pragma unroll
        for (int r = 0; r < 4; ++r) {
          int m = row0 + wr * 128 + mi * 16 + 4 * g + r;
          int b = m >> 11, tt = m & 2047;
          out[(((size_t)(b * NH_ + h)) * T_SEQ + tt) * HD_ + d] = f2b((acc[mi][ni][r] + bv) * qscale);
        }
      }
  } else if (sel == 1) { // K: [B,NH,T,HD] + intra-64 row permutation
    unsigned short* out = Ko;
#pragma unroll
    for (int mi = 0; mi < 8; ++mi)
#pragma unroll
      for (int ni = 0; ni < 4; ++ni) {
        int n = col0 + wc * 64 + ni * 16 + ln;
        float bv = bias[n];
        int h = n >> 7, d = n & 127;
#pragma unroll
        for (int r = 0; r < 4; ++r) {
          int m = row0 + wr * 128 + mi * 16 + 4 * g + r;
          int b = m >> 11, tt = m & 2047;
          int tl = tt & 63;
          int tp = (tt & ~63) | ((tl >> 5) * 32 + ((tl >> 2) & 1) * 16 + ((tl >> 3) & 3) * 4 + (tl & 3));
          out[(((size_t)(b * NH_ + h)) * T_SEQ + tp) * HD_ + d] = f2b(acc[mi][ni][r] + bv);
        }
      }
  } else { // V: transposed [B,NH,HD,T]
    unsigned short* out = Vo;
#pragma unroll
    for (int mi = 0; mi < 8; ++mi)
#pragma unroll
      for (int ni = 0; ni < 4; ++ni) {
        int n = col0 + wc * 64 + ni * 16 + ln;
        float bv = bias[n];
        int h = n >> 7, d = n & 127;
        int m0 = row0 + wr * 128 + mi * 16 + 4 * g;
        int b = m0 >> 11, t0 = m0 & 2047;
        u16x4 pk;
#pragma unroll
        for (int r = 0; r < 4; ++r) pk[r] = f2b(acc[mi][ni][r] + bv);
        *(u16x4*)&out[(((size_t)(b * NH_ + h)) * HD_ + d) * T_SEQ + t0] = pk;
      }
  }
#undef ST_A
#undef ST_B
#undef STAGE_A0
#undef STAGE_A1
#undef STAGE_B0
#undef STAGE_B1
#undef READ_A
#undef READ_B
#undef MFMA_PHASE
#undef BARRIER
}

// ---------------- output-projection GEMM (r12-verified, f32 out) ----------
__global__ __launch_bounds__(512, 2) void gemm_out_k(const unsigned short* __restrict__ A,
                                                     const unsigned short* __restrict__ W,
                                                     const float* __restrict__ bias,
                                                     float* __restrict__ outp) {
  constexpr int K = H_DIM;   // 2048
  constexpr int NT = K / 64; // 32 K-tiles
  __shared__ __align__(16) unsigned short Al[2][256 * 64];
  __shared__ __align__(16) unsigned short Bl[2][256 * 64];

  const int tid = threadIdx.x;
  const int w = tid >> 6, l = tid & 63;
  const int g = l >> 4, ln = l & 15;
  const int wr = w >> 2, wc = w & 3;

  const int bid = blockIdx.x + gridDim.x * blockIdx.y;
  const int fid = ((bid & 7) << 5) | (bid >> 3);
  const int col0 = (fid & 7) * 256;
  const int row0 = (fid >> 3) * 256;

  const char* Ag = (const char*)A;
  const char* Wg = (const char*)W;

  const int srow = l >> 3;
  const int sbyte = ((l & 7) * 16) ^ (srow << 4);

#define ST_A(t2, b2, c)                                                                 \
  gload16(Ag + (((size_t)(row0 + (c) * 8 + srow)) * K + (t2) * 64) * 2 + sbyte,         \
          (char*)&Al[b2][0] + (c) * 1024)
#define ST_B(t2, b2, c)                                                                 \
  gload16(Wg + (((size_t)(col0 + (c) * 8 + srow)) * K + (t2) * 64) * 2 + sbyte,         \
          (char*)&Bl[b2][0] + (c) * 1024)
#define STAGE_A0(t2, b2) do { ST_A(t2, b2, w);  ST_A(t2, b2, 16 + w); } while (0)
#define STAGE_A1(t2, b2) do { ST_A(t2, b2, 8 + w); ST_A(t2, b2, 24 + w); } while (0)
#define STAGE_B0(t2, b2) do { int c_ = (w >> 2) * 8 + (w & 3); ST_B(t2, b2, c_); ST_B(t2, b2, 16 + c_); } while (0)
#define STAGE_B1(t2, b2) do { int c_ = (w >> 2) * 8 + 4 + (w & 3); ST_B(t2, b2, c_); ST_B(t2, b2, 16 + c_); } while (0)

  f32x4 acc[8][4] = {};
  bf16x8 aF[4][2];
  bf16x8 bF[2][2][2];

#define READ_A(mh)                                                                      \
  _Pragma("unroll") for (int mf = 0; mf < 4; ++mf)                                      \
  _Pragma("unroll") for (int ks = 0; ks < 2; ++ks) {                                    \
    int row_ = wr * 128 + (mh) * 64 + mf * 16 + ln;                                     \
    aF[mf][ks] = *(const bf16x8*)((const char*)Ab + row_ * 128 +                        \
                                  ((ks * 64 + g * 16) ^ ((ln & 7) << 4)));              \
  }
#define READ_B(nh)                                                                      \
  _Pragma("unroll") for (int nf = 0; nf < 2; ++nf)                                      \
  _Pragma("unroll") for (int ks = 0; ks < 2; ++ks) {                                    \
    int row_ = wc * 64 + (nh) * 32 + nf * 16 + ln;                                      \
    bF[nh][nf][ks] = *(const bf16x8*)((const char*)Bb + row_ * 128 +                    \
                                      ((ks * 64 + g * 16) ^ ((ln & 7) << 4)));          \
  }
#define MFMA_PHASE(mh, nh)                                                              \
  do {                                                                                  \
    __builtin_amdgcn_s_setprio(1);                                                      \
    _Pragma("unroll") for (int mf = 0; mf < 4; ++mf)                                    \
    _Pragma("unroll") for (int nf = 0; nf < 2; ++nf)                                    \
    _Pragma("unroll") for (int ks = 0; ks < 2; ++ks)                                    \
      acc[(mh) * 4 + mf][(nh) * 2 + nf] = __builtin_amdgcn_mfma_f32_16x16x32_bf16(      \
          aF[mf][ks], bF[nh][nf][ks], acc[(mh) * 4 + mf][(nh) * 2 + nf], 0, 0, 0);      \
    __builtin_amdgcn_s_setprio(0);                                                      \
  } while (0)
#define BARRIER() asm volatile("s_barrier" ::: "memory")

  STAGE_A0(0, 0); STAGE_B0(0, 0); STAGE_B1(0, 0); STAGE_A1(0, 0);
  STAGE_A0(1, 1); STAGE_B0(1, 1); STAGE_B1(1, 1); STAGE_A1(1, 1);
  asm volatile("s_waitcnt vmcnt(8)" ::: "memory");
  BARRIER();

#pragma unroll 1
  for (int t = 0; t < NT; ++t) {
    const int buf = t & 1;
    const unsigned short* Ab = &Al[buf][0];
    const unsigned short* Bb = &Bl[buf][0];
    READ_A(0); READ_B(0);
    if (t >= 1 && t + 1 < NT) STAGE_A1(t + 1, (t + 1) & 1);
    BARRIER();
    MFMA_PHASE(0, 0);
    BARRIER();
    READ_B(1);
    if (t + 2 < NT) STAGE_A0(t + 2, buf);
    BARRIER();
    MFMA_PHASE(0, 1);
    BARRIER();
    READ_A(1);
    if (t + 2 < NT) STAGE_B0(t + 2, buf);
    BARRIER();
    MFMA_PHASE(1, 0);
    BARRIER();
    if (t + 2 < NT) {
      STAGE_B1(t + 2, buf);
      asm volatile("s_waitcnt vmcnt(6)" ::: "memory");
    } else {
      asm volatile("s_waitcnt vmcnt(0)" ::: "memory");
    }
    BARRIER();
    MFMA_PHASE(1, 1);
    BARRIER();
  }

#pragma unroll
  for (int mi = 0; mi < 8; ++mi)
#pragma unroll
    for (int ni = 0; ni < 4; ++ni) {
      int n = col0 + wc * 64 + ni * 16 + ln;
      float bv = bias[n];
#pragma unroll
      for (int r = 0; r < 4; ++r) {
        int m = row0 + wr * 128 + mi * 16 + 4 * g + r;
        outp[(size_t)m * H_DIM + n] = acc[mi][ni][r] + bv;
      }
    }
#undef ST_A
#undef ST_B
#undef STAGE_A0
#undef STAGE_A1
#undef STAGE_B0
#undef STAGE_B1
#undef READ_A
#undef READ_B
#undef MFMA_PHASE
#undef BARRIER
}

// ---------------- causal flash attention (r16-verified, ~104 us) ----------------
// QBLK=128 (4 waves), 512 blocks, serial q-tile pair (15-pr, pr) -> 34 iters each;
// 2 blocks/CU. K rows pre-permuted -> shuffle-free P routing; in-reg P.
__global__ __launch_bounds__(256, 2) void attn128_k(const unsigned short* __restrict__ Q,
                                                    const unsigned short* __restrict__ Kg,
                                                    const unsigned short* __restrict__ Vt,
                                                    unsigned short* __restrict__ ctx) {
  __shared__ __align__(16) unsigned short Kl[2][64 * 128]; // [kv-slot][k] swizzled rows (256B)
  __shared__ __align__(16) unsigned short Vl[2][128 * 64]; // [d][kv] swizzled rows (128B)

  const int tid = threadIdx.x;
  const int w = tid >> 6, l = tid & 63;   // w: 0..3
  const int g = l >> 4, ln = l & 15;

  // XCD grouping: 512 blocks -> 64 consecutive per XCD; each bh's 8 blocks on one XCD
  const int flat = ((blockIdx.x & 7) << 6) | (blockIdx.x >> 3);
  const int bh = flat >> 3;  // 0..63
  const int pr = flat & 7;   // 0..7 -> q-tile pair (15-pr, pr)

  const char* kbase = (const char*)(Kg + (size_t)bh * T_SEQ * HD_);
  const char* vbase = (const char*)(Vt + (size_t)bh * HD_ * T_SEQ);
  const int b = bh >> 4, h = bh & 15;

#define STAGE_KV(bufi, ktile) do {                                                    \
    int kv0_ = (ktile) * 64;                                                          \
    _Pragma("unroll")                                                                 \
    for (int i_ = 0; i_ < 4; ++i_) {                                                  \
      int c_ = w * 4 + i_;                                                            \
      int kvr_ = c_ * 4 + g;                                                          \
      gload16(kbase + ((size_t)(kv0_ + kvr_) * HD_) * 2 + ((ln * 16) ^ ((kvr_ & 7) << 4)), \
              (char*)&Kl[bufi][0] + c_ * 1024);                                       \
      int d_ = c_ * 8 + (l >> 3);                                                     \
      gload16(vbase + ((size_t)d_ * T_SEQ + kv0_) * 2 + (((l & 7) * 16) ^ ((d_ & 7) << 4)), \
              (char*)&Vl[bufi][0] + c_ * 1024);                                       \
    } } while (0)

#pragma unroll 1
  for (int half = 0; half < 2; ++half) {
    const int qt = half ? pr : (15 - pr); // heavy 128-row tile first
    const int q0 = qt << 7;
    const int qw = q0 + w * 32;           // wave's first q row

    bf16x8 bq[2][4];
#pragma unroll
    for (int f = 0; f < 2; ++f)
#pragma unroll
      for (int kk = 0; kk < 4; ++kk)
        bq[f][kk] = *(const bf16x8*)(Q + ((size_t)bh * T_SEQ + qw + f * 16 + ln) * HD_ + kk * 32 + g * 8);

    f32x4 acc[2][8] = {};
    float mrun[2] = {-INFINITY, -INFINITY};
    float lrun[2] = {0.f, 0.f};

    const int nt = (qt + 1) * 2;

    STAGE_KV(0, 0);
    __syncthreads();
    int cur = 0;

#pragma unroll 1
    for (int kt = 0; kt < nt; ++kt) {
      if (kt + 1 < nt) STAGE_KV(cur ^ 1, kt + 1); // prefetch overlaps compute
      const int kv0 = kt * 64;
      if (kv0 <= qw + 31) { // causal wave-skip (barriers stay outside)
        const char* kl = (const char*)&Kl[cur][0];
        const char* vl = (const char*)&Vl[cur][0];

        // S^T[kv-slot][q] = K . Q^T
        f32x4 st[2][4] = {};
        __builtin_amdgcn_s_setprio(1);
#pragma unroll
        for (int kk = 0; kk < 4; ++kk) {
          bf16x8 ak[4];
#pragma unroll
          for (int mf = 0; mf < 4; ++mf)
            ak[mf] = *(const bf16x8*)(kl + (mf * 16 + ln) * 256 + ((kk * 64 + g * 16) ^ ((ln & 7) << 4)));
#pragma unroll
          for (int mf = 0; mf < 4; ++mf) {
            st[0][mf] = __builtin_amdgcn_mfma_f32_16x16x32_bf16(ak[mf], bq[0][kk], st[0][mf], 0, 0, 0);
            st[1][mf] = __builtin_amdgcn_mfma_f32_16x16x32_bf16(ak[mf], bq[1][kk], st[1][mf], 0, 0, 0);
          }
        }
        __builtin_amdgcn_s_setprio(0);

        // causal mask: slot (mf,g,r) holds TRUE kv = kv0 + 32(mf>>1) + 8g + 4(mf&1) + r
        if (kv0 + 63 > qw) {
#pragma unroll
          for (int f = 0; f < 2; ++f)
#pragma unroll
            for (int mf = 0; mf < 4; ++mf)
#pragma unroll
              for (int r = 0; r < 4; ++r)
                if (kv0 + 32 * (mf >> 1) + 8 * g + 4 * (mf & 1) + r > qw + f * 16 + ln)
                  st[f][mf][r] = -INFINITY;
        }

        bf16x8 ap[2][2]; // [f][ks]
#pragma unroll
        for (int f = 0; f < 2; ++f) {
          float pmax = -INFINITY;
#pragma unroll
          for (int mf = 0; mf < 4; ++mf)
#pragma unroll
            for (int r = 0; r < 4; ++r) pmax = fmaxf(pmax, st[f][mf][r]);
          pmax = fmaxf(pmax, __shfl_xor(pmax, 16));
          pmax = fmaxf(pmax, __shfl_xor(pmax, 32));
          float msub = mrun[f];
          if (__any(pmax > mrun[f] + 8.f)) { // defer-max
            msub = fmaxf(mrun[f], pmax);
            float fac = __builtin_amdgcn_exp2f(mrun[f] - msub);
            mrun[f] = msub;
            lrun[f] *= fac;
            float fr[4];
#pragma unroll
            for (int r = 0; r < 4; ++r) fr[r] = __shfl(fac, g * 4 + r);
#pragma unroll
            for (int nf = 0; nf < 8; ++nf) {
              acc[f][nf][0] *= fr[0]; acc[f][nf][1] *= fr[1];
              acc[f][nf][2] *= fr[2]; acc[f][nf][3] *= fr[3];
            }
          }
          uint32_t Aq[4][2];
          float psum = 0.f;
#pragma unroll
          for (int mf = 0; mf < 4; ++mf) {
            float p0 = __builtin_amdgcn_exp2f(st[f][mf][0] - msub);
            float p1 = __builtin_amdgcn_exp2f(st[f][mf][1] - msub);
            float p2 = __builtin_amdgcn_exp2f(st[f][mf][2] - msub);
            float p3 = __builtin_amdgcn_exp2f(st[f][mf][3] - msub);
            psum += (p0 + p1) + (p2 + p3);
            asm("v_cvt_pk_bf16_f32 %0, %1, %2" : "=v"(Aq[mf][0]) : "v"(p0), "v"(p1));
            asm("v_cvt_pk_bf16_f32 %0, %1, %2" : "=v"(Aq[mf][1]) : "v"(p2), "v"(p3));
          }
          psum += __shfl_xor(psum, 16);
          psum += __shfl_xor(psum, 32);
          lrun[f] += psum;

          // shuffle-free routing (K-row permutation): ap[ks] = {Aq[2ks], Aq[2ks+1]}
#pragma unroll
          for (int ks = 0; ks < 2; ++ks) {
            union { uint32_t u[4]; bf16x8 v; } t;
            t.u[0] = Aq[2 * ks][0];     t.u[1] = Aq[2 * ks][1];
            t.u[2] = Aq[2 * ks + 1][0]; t.u[3] = Aq[2 * ks + 1][1];
            ap[f][ks] = t.v;
          }
        }

        __builtin_amdgcn_s_setprio(1);
#pragma unroll
        for (int nf = 0; nf < 8; ++nf) {
          int d = nf * 16 + ln;
#pragma unroll
          for (int ks = 0; ks < 2; ++ks) {
            bf16x8 bv = *(const bf16x8*)(vl + d * 128 + ((ks * 64 + g * 16) ^ ((ln & 7) << 4)));
            acc[0][nf] = __builtin_amdgcn_mfma_f32_16x16x32_bf16(ap[0][ks], bv, acc[0][nf], 0, 0, 0);
            acc[1][nf] = __builtin_amdgcn_mfma_f32_16x16x32_bf16(ap[1][ks], bv, acc[1][nf], 0, 0, 0);
          }
        }
        __builtin_amdgcn_s_setprio(0);
      }
      __syncthreads();
      cur ^= 1;
    }

    // epilogue: divide by row sum, write ctx [B, T, NH*HD]
#pragma unroll
    for (int f = 0; f < 2; ++f) {
      float inv[4];
#pragma unroll
      for (int r = 0; r < 4; ++r) inv[r] = 1.f / __shfl(lrun[f], g * 4 + r);
#pragma unroll
      for (int nf = 0; nf < 8; ++nf) {
#pragma unroll
        for (int r = 0; r < 4; ++r) {
          int qrow = qw + f * 16 + g * 4 + r;
          ctx[((size_t)(b * T_SEQ + qrow)) * H_DIM + h * HD_ + nf * 16 + ln] =
              f2b(acc[f][nf][r] * inv[r]);
        }
      }
    }
  }
#undef STAGE_KV
}

// ---------------- host launch ----------------
extern "C" void kernel_launch(void* const* d_in, const int* in_sizes, int n_in,
                              void* d_out, int out_size, void* d_ws, size_t ws_size,
                              hipStream_t stream) {
  (void)in_sizes; (void)n_in; (void)out_size; (void)ws_size;
  const float* x  = (const float*)d_in[0];
  const float* qw = (const float*)d_in[1];
  const float* qb = (const float*)d_in[2];
  const float* kw = (const float*)d_in[3];
  const float* kb = (const float*)d_in[4];
  const float* vw = (const float*)d_in[5];
  const float* vb = (const float*)d_in[6];
  const float* ow = (const float*)d_in[7];
  const float* ob = (const float*)d_in[8];

  char* ws = (char*)d_ws;
  unsigned short* xb  = (unsigned short*)(ws);              // 32 MiB (x bf16; later reused as ctx)
  unsigned short* qwb = (unsigned short*)(ws + 33554432);   // 8 MiB
  unsigned short* kwb = (unsigned short*)(ws + 41943040);
  unsigned short* vwb = (unsigned short*)(ws + 50331648);
  unsigned short* owb = (unsigned short*)(ws + 58720256);
  unsigned short* Qb  = (unsigned short*)(ws + 67108864);   // 32 MiB [B,NH,T,HD]
  unsigned short* Kb  = (unsigned short*)(ws + 100663296);  // 32 MiB (row-permuted per 64)
  unsigned short* Vtb = (unsigned short*)(ws + 134217728);  // 32 MiB [B,NH,HD,T]
  unsigned short* ctxb = xb;                                // alias: x dead after V proj

  const float cscale = 0.08838834764831845f * 1.4426950408889634f; // SCALE * log2(e)

  // all f32->bf16 conversions in ONE launch (x + 4 weight matrices)
  cvt_all_k<<<2048, dim3(256), 0, stream>>>(x, qw, kw, vw, ow, xb, qwb, kwb, vwb, owb);

  // fused Q/K/V projections: one 768-block launch (one dispatch tail, not three)
  qkv_gemm_k<<<dim3(768), dim3(512), 0, stream>>>(xb, qwb, kwb, vwb, qb, kb, vb,
                                                  Qb, Kb, Vtb, cscale);

  attn128_k<<<dim3(512), dim3(256), 0, stream>>>(Qb, Kb, Vtb, ctxb);

  gemm_out_k<<<dim3(8, 32), dim3(512), 0, stream>>>(ctxb, owb, ob, (float*)d_out);
}

// Round 22
// 371.894 us; speedup vs baseline: 1.3288x; 1.0007x over previous
//
#include <hip/hip_runtime.h>
#include <stdint.h>

// Problem constants
#define B_SZ 4
#define T_SEQ 2048
#define H_DIM 2048
#define NH_ 16
#define HD_ 128
#define MTOK (B_SZ * T_SEQ) // 8192

typedef __attribute__((ext_vector_type(8))) short bf16x8;
typedef __attribute__((ext_vector_type(4))) float f32x4;
typedef __attribute__((ext_vector_type(4))) unsigned short u16x4;

__device__ __forceinline__ unsigned short f2b(float f) {
  union { float f; uint32_t u; } x; x.f = f;
  uint32_t r = x.u + 0x7FFFu + ((x.u >> 16) & 1u); // RNE
  return (unsigned short)(r >> 16);
}

__device__ __forceinline__ void gload16(const void* g, void* l) {
  // width-16 global->LDS DMA; LDS dest is wave-uniform base, HW scatters lane*16
  __builtin_amdgcn_global_load_lds((const __attribute__((address_space(1))) void*)g,
                                   (__attribute__((address_space(3))) void*)l, 16, 0, 0);
}

// ---------------- f32 -> bf16 conversion: x + 4 weights in ONE launch ----------------
// 8M float4 groups total: i < 4M -> x; else weight sel = (i-4M)>>20 (1M each).
__global__ void cvt_all_k(const float* __restrict__ x,
                          const float* __restrict__ s0, const float* __restrict__ s1,
                          const float* __restrict__ s2, const float* __restrict__ s3,
                          unsigned short* __restrict__ xd,
                          unsigned short* __restrict__ d0, unsigned short* __restrict__ d1,
                          unsigned short* __restrict__ d2, unsigned short* __restrict__ d3) {
  const int nx4 = (MTOK * H_DIM) / 4;     // 4M
  const int nw4 = (H_DIM * H_DIM) / 4;    // 1M
  const int ntot = nx4 + 4 * nw4;         // 8M
  for (int i = blockIdx.x * blockDim.x + threadIdx.x; i < ntot; i += gridDim.x * blockDim.x) {
    const float* src;
    unsigned short* dst;
    int j;
    if (i < nx4) {
      src = x; dst = xd; j = i;
    } else {
      int k = i - nx4;
      int sel = k >> 20; j = k & (nw4 - 1);
      src = sel == 0 ? s0 : sel == 1 ? s1 : sel == 2 ? s2 : s3;
      dst = sel == 0 ? d0 : sel == 1 ? d1 : sel == 2 ? d2 : d3;
    }
    float4 v = ((const float4*)src)[j];
    u16x4 o;
    o[0] = f2b(v.x); o[1] = f2b(v.y); o[2] = f2b(v.z); o[3] = f2b(v.w);
    ((u16x4*)dst)[j] = o;
  }
}

// ---------------- fused QKV GEMM: 768 blocks, sel = bid>>8 picks matrix ----------
// K-loop identical to the r12-verified gemm256_k. One launch instead of three.
// sel 0: Q -> [B,NH,T,HD], pre-scaled by qscale
// sel 1: K -> [B,NH,T,HD] with intra-64 kv row permutation (shuffle-free attn routing)
// sel 2: V -> [B,NH,HD,T] transposed
__global__ __launch_bounds__(512, 2) void qkv_gemm_k(const unsigned short* __restrict__ xA,
                                                     const unsigned short* __restrict__ qwb,
                                                     const unsigned short* __restrict__ kwb,
                                                     const unsigned short* __restrict__ vwb,
                                                     const float* __restrict__ qb,
                                                     const float* __restrict__ kb,
                                                     const float* __restrict__ vb,
                                                     unsigned short* __restrict__ Qo,
                                                     unsigned short* __restrict__ Ko,
                                                     unsigned short* __restrict__ Vo,
                                                     float qscale) {
  constexpr int K = H_DIM;   // 2048
  constexpr int NT = K / 64; // 32 K-tiles
  __shared__ __align__(16) unsigned short Al[2][256 * 64];
  __shared__ __align__(16) unsigned short Bl[2][256 * 64];

  const int tid = threadIdx.x;
  const int w = tid >> 6, l = tid & 63;
  const int g = l >> 4, ln = l & 15;
  const int wr = w >> 2, wc = w & 3;

  const int bid0 = blockIdx.x;
  const int sel = bid0 >> 8;       // 0:Q 1:K 2:V (wave-uniform)
  const int bid = bid0 & 255;
  const int fid = ((bid & 7) << 5) | (bid >> 3);
  const int col0 = (fid & 7) * 256;
  const int row0 = (fid >> 3) * 256;

  const unsigned short* Wm = sel == 0 ? qwb : sel == 1 ? kwb : vwb;
  const float* bias = sel == 0 ? qb : sel == 1 ? kb : vb;

  const char* Ag = (const char*)xA;
  const char* Wg = (const char*)Wm;

  const int srow = l >> 3;
  const int sbyte = ((l & 7) * 16) ^ (srow << 4);

#define ST_A(t2, b2, c)                                                                 \
  gload16(Ag + (((size_t)(row0 + (c) * 8 + srow)) * K + (t2) * 64) * 2 + sbyte,         \
          (char*)&Al[b2][0] + (c) * 1024)
#define ST_B(t2, b2, c)                                                                 \
  gload16(Wg + (((size_t)(col0 + (c) * 8 + srow)) * K + (t2) * 64) * 2 + sbyte,         \
          (char*)&Bl[b2][0] + (c) * 1024)
#define STAGE_A0(t2, b2) do { ST_A(t2, b2, w);  ST_A(t2, b2, 16 + w); } while (0)
#define STAGE_A1(t2, b2) do { ST_A(t2, b2, 8 + w); ST_A(t2, b2, 24 + w); } while (0)
#define STAGE_B0(t2, b2) do { int c_ = (w >> 2) * 8 + (w & 3); ST_B(t2, b2, c_); ST_B(t2, b2, 16 + c_); } while (0)
#define STAGE_B1(t2, b2) do { int c_ = (w >> 2) * 8 + 4 + (w & 3); ST_B(t2, b2, c_); ST_B(t2, b2, 16 + c_); } while (0)

  f32x4 acc[8][4] = {};
  bf16x8 aF[4][2];
  bf16x8 bF[2][2][2];

#define READ_A(mh)                                                                      \
  _Pragma("unroll") for (int mf = 0; mf < 4; ++mf)                                      \
  _Pragma("unroll") for (int ks = 0; ks < 2; ++ks) {                                    \
    int row_ = wr * 128 + (mh) * 64 + mf * 16 + ln;                                     \
    aF[mf][ks] = *(const bf16x8*)((const char*)Ab + row_ * 128 +                        \
                                  ((ks * 64 + g * 16) ^ ((ln & 7) << 4)));              \
  }
#define READ_B(nh)                                                                      \
  _Pragma("unroll") for (int nf = 0; nf < 2; ++nf)                                      \
  _Pragma("unroll") for (int ks = 0; ks < 2; ++ks) {                                    \
    int row_ = wc * 64 + (nh) * 32 + nf * 16 + ln;                                      \
    bF[nh][nf][ks] = *(const bf16x8*)((const char*)Bb + row_ * 128 +                    \
                                      ((ks * 64 + g * 16) ^ ((ln & 7) << 4)));          \
  }
#define MFMA_PHASE(mh, nh)                                                              \
  do {                                                                                  \
    __builtin_amdgcn_s_setprio(1);                                                      \
    _Pragma("unroll") for (int mf = 0; mf < 4; ++mf)                                    \
    _Pragma("unroll") for (int nf = 0; nf < 2; ++nf)                                    \
    _Pragma("unroll") for (int ks = 0; ks < 2; ++ks)                                    \
      acc[(mh) * 4 + mf][(nh) * 2 + nf] = __builtin_amdgcn_mfma_f32_16x16x32_bf16(      \
          aF[mf][ks], bF[nh][nf][ks], acc[(mh) * 4 + mf][(nh) * 2 + nf], 0, 0, 0);      \
    __builtin_amdgcn_s_setprio(0);                                                      \
  } while (0)
#define BARRIER() asm volatile("s_barrier" ::: "memory")

  STAGE_A0(0, 0); STAGE_B0(0, 0); STAGE_B1(0, 0); STAGE_A1(0, 0);
  STAGE_A0(1, 1); STAGE_B0(1, 1); STAGE_B1(1, 1); STAGE_A1(1, 1);
  asm volatile("s_waitcnt vmcnt(8)" ::: "memory");
  BARRIER();

#pragma unroll 1
  for (int t = 0; t < NT; ++t) {
    const int buf = t & 1;
    const unsigned short* Ab = &Al[buf][0];
    const unsigned short* Bb = &Bl[buf][0];
    READ_A(0); READ_B(0);
    if (t >= 1 && t + 1 < NT) STAGE_A1(t + 1, (t + 1) & 1);
    BARRIER();
    MFMA_PHASE(0, 0);
    BARRIER();
    READ_B(1);
    if (t + 2 < NT) STAGE_A0(t + 2, buf);
    BARRIER();
    MFMA_PHASE(0, 1);
    BARRIER();
    READ_A(1);
    if (t + 2 < NT) STAGE_B0(t + 2, buf);
    BARRIER();
    MFMA_PHASE(1, 0);
    BARRIER();
    if (t + 2 < NT) {
      STAGE_B1(t + 2, buf);
      asm volatile("s_waitcnt vmcnt(6)" ::: "memory");
    } else {
      asm volatile("s_waitcnt vmcnt(0)" ::: "memory");
    }
    BARRIER();
    MFMA_PHASE(1, 1);
    BARRIER();
  }

  // ---- epilogue (uniform branch on sel) ----
  if (sel == 0) { // Q: [B,NH,T,HD], pre-scaled
    unsigned short* out = Qo;
#pragma unroll
    for (int mi = 0; mi < 8; ++mi)
#pragma unroll
      for (int ni = 0; ni < 4; ++ni) {
        int n = col0 + wc * 64 + ni * 16 + ln;
        float bv = bias[n];
        int h = n >> 7, d = n & 127;
#pragma unroll
        for (int r = 0; r < 4; ++r) {
          int m = row0 + wr * 128 + mi * 16 + 4 * g + r;
          int b = m >> 11, tt = m & 2047;
          out[(((size_t)(b * NH_ + h)) * T_SEQ + tt) * HD_ + d] = f2b((acc[mi][ni][r] + bv) * qscale);
        }
      }
  } else if (sel == 1) { // K: [B,NH,T,HD] + intra-64 row permutation
    unsigned short* out = Ko;
#pragma unroll
    for (int mi = 0; mi < 8; ++mi)
#pragma unroll
      for (int ni = 0; ni < 4; ++ni) {
        int n = col0 + wc * 64 + ni * 16 + ln;
        float bv = bias[n];
        int h = n >> 7, d = n & 127;
#pragma unroll
        for (int r = 0; r < 4; ++r) {
          int m = row0 + wr * 128 + mi * 16 + 4 * g + r;
          int b = m >> 11, tt = m & 2047;
          int tl = tt & 63;
          int tp = (tt & ~63) | ((tl >> 5) * 32 + ((tl >> 2) & 1) * 16 + ((tl >> 3) & 3) * 4 + (tl & 3));
          out[(((size_t)(b * NH_ + h)) * T_SEQ + tp) * HD_ + d] = f2b(acc[mi][ni][r] + bv);
        }
      }
  } else { // V: transposed [B,NH,HD,T]
    unsigned short* out = Vo;
#pragma unroll
    for (int mi = 0; mi < 8; ++mi)
#pragma unroll
      for (int ni = 0; ni < 4; ++ni) {
        int n = col0 + wc * 64 + ni * 16 + ln;
        float bv = bias[n];
        int h = n >> 7, d = n & 127;
        int m0 = row0 + wr * 128 + mi * 16 + 4 * g;
        int b = m0 >> 11, t0 = m0 & 2047;
        u16x4 pk;
#pragma unroll
        for (int r = 0; r < 4; ++r) pk[r] = f2b(acc[mi][ni][r] + bv);
        *(u16x4*)&out[(((size_t)(b * NH_ + h)) * HD_ + d) * T_SEQ + t0] = pk;
      }
  }
#undef ST_A
#undef ST_B
#undef STAGE_A0
#undef STAGE_A1
#undef STAGE_B0
#undef STAGE_B1
#undef READ_A
#undef READ_B
#undef MFMA_PHASE
#undef BARRIER
}

// ---------------- output-projection GEMM (r12-verified, f32 out) ----------
__global__ __launch_bounds__(512, 2) void gemm_out_k(const unsigned short* __restrict__ A,
                                                     const unsigned short* __restrict__ W,
                                                     const float* __restrict__ bias,
                                                     float* __restrict__ outp) {
  constexpr int K = H_DIM;   // 2048
  constexpr int NT = K / 64; // 32 K-tiles
  __shared__ __align__(16) unsigned short Al[2][256 * 64];
  __shared__ __align__(16) unsigned short Bl[2][256 * 64];

  const int tid = threadIdx.x;
  const int w = tid >> 6, l = tid & 63;
  const int g = l >> 4, ln = l & 15;
  const int wr = w >> 2, wc = w & 3;

  const int bid = blockIdx.x + gridDim.x * blockIdx.y;
  const int fid = ((bid & 7) << 5) | (bid >> 3);
  const int col0 = (fid & 7) * 256;
  const int row0 = (fid >> 3) * 256;

  const char* Ag = (const char*)A;
  const char* Wg = (const char*)W;

  const int srow = l >> 3;
  const int sbyte = ((l & 7) * 16) ^ (srow << 4);

#define ST_A(t2, b2, c)                                                                 \
  gload16(Ag + (((size_t)(row0 + (c) * 8 + srow)) * K + (t2) * 64) * 2 + sbyte,         \
          (char*)&Al[b2][0] + (c) * 1024)
#define ST_B(t2, b2, c)                                                                 \
  gload16(Wg + (((size_t)(col0 + (c) * 8 + srow)) * K + (t2) * 64) * 2 + sbyte,         \
          (char*)&Bl[b2][0] + (c) * 1024)
#define STAGE_A0(t2, b2) do { ST_A(t2, b2, w);  ST_A(t2, b2, 16 + w); } while (0)
#define STAGE_A1(t2, b2) do { ST_A(t2, b2, 8 + w); ST_A(t2, b2, 24 + w); } while (0)
#define STAGE_B0(t2, b2) do { int c_ = (w >> 2) * 8 + (w & 3); ST_B(t2, b2, c_); ST_B(t2, b2, 16 + c_); } while (0)
#define STAGE_B1(t2, b2) do { int c_ = (w >> 2) * 8 + 4 + (w & 3); ST_B(t2, b2, c_); ST_B(t2, b2, 16 + c_); } while (0)

  f32x4 acc[8][4] = {};
  bf16x8 aF[4][2];
  bf16x8 bF[2][2][2];

#define READ_A(mh)                                                                      \
  _Pragma("unroll") for (int mf = 0; mf < 4; ++mf)                                      \
  _Pragma("unroll") for (int ks = 0; ks < 2; ++ks) {                                    \
    int row_ = wr * 128 + (mh) * 64 + mf * 16 + ln;                                     \
    aF[mf][ks] = *(const bf16x8*)((const char*)Ab + row_ * 128 +                        \
                                  ((ks * 64 + g * 16) ^ ((ln & 7) << 4)));              \
  }
#define READ_B(nh)                                                                      \
  _Pragma("unroll") for (int nf = 0; nf < 2; ++nf)                                      \
  _Pragma("unroll") for (int ks = 0; ks < 2; ++ks) {                                    \
    int row_ = wc * 64 + (nh) * 32 + nf * 16 + ln;                                      \
    bF[nh][nf][ks] = *(const bf16x8*)((const char*)Bb + row_ * 128 +                    \
                                      ((ks * 64 + g * 16) ^ ((ln & 7) << 4)));          \
  }
#define MFMA_PHASE(mh, nh)                                                              \
  do {                                                                                  \
    __builtin_amdgcn_s_setprio(1);                                                      \
    _Pragma("unroll") for (int mf = 0; mf < 4; ++mf)                                    \
    _Pragma("unroll") for (int nf = 0; nf < 2; ++nf)                                    \
    _Pragma("unroll") for (int ks = 0; ks < 2; ++ks)                                    \
      acc[(mh) * 4 + mf][(nh) * 2 + nf] = __builtin_amdgcn_mfma_f32_16x16x32_bf16(      \
          aF[mf][ks], bF[nh][nf][ks], acc[(mh) * 4 + mf][(nh) * 2 + nf], 0, 0, 0);      \
    __builtin_amdgcn_s_setprio(0);                                                      \
  } while (0)
#define BARRIER() asm volatile("s_barrier" ::: "memory")

  STAGE_A0(0, 0); STAGE_B0(0, 0); STAGE_B1(0, 0); STAGE_A1(0, 0);
  STAGE_A0(1, 1); STAGE_B0(1, 1); STAGE_B1(1, 1); STAGE_A1(1, 1);
  asm volatile("s_waitcnt vmcnt(8)" ::: "memory");
  BARRIER();

#pragma unroll 1
  for (int t = 0; t < NT; ++t) {
    const int buf = t & 1;
    const unsigned short* Ab = &Al[buf][0];
    const unsigned short* Bb = &Bl[buf][0];
    READ_A(0); READ_B(0);
    if (t >= 1 && t + 1 < NT) STAGE_A1(t + 1, (t + 1) & 1);
    BARRIER();
    MFMA_PHASE(0, 0);
    BARRIER();
    READ_B(1);
    if (t + 2 < NT) STAGE_A0(t + 2, buf);
    BARRIER();
    MFMA_PHASE(0, 1);
    BARRIER();
    READ_A(1);
    if (t + 2 < NT) STAGE_B0(t + 2, buf);
    BARRIER();
    MFMA_PHASE(1, 0);
    BARRIER();
    if (t + 2 < NT) {
      STAGE_B1(t + 2, buf);
      asm volatile("s_waitcnt vmcnt(6)" ::: "memory");
    } else {
      asm volatile("s_waitcnt vmcnt(0)" ::: "memory");
    }
    BARRIER();
    MFMA_PHASE(1, 1);
    BARRIER();
  }

#pragma unroll
  for (int mi = 0; mi < 8; ++mi)
#pragma unroll
    for (int ni = 0; ni < 4; ++ni) {
      int n = col0 + wc * 64 + ni * 16 + ln;
      float bv = bias[n];
#pragma unroll
      for (int r = 0; r < 4; ++r) {
        int m = row0 + wr * 128 + mi * 16 + 4 * g + r;
        outp[(size_t)m * H_DIM + n] = acc[mi][ni][r] + bv;
      }
    }
#undef ST_A
#undef ST_B
#undef STAGE_A0
#undef STAGE_A1
#undef STAGE_B0
#undef STAGE_B1
#undef READ_A
#undef READ_B
#undef MFMA_PHASE
#undef BARRIER
}

// ---------------- causal flash attention (r16-verified, ~104 us) ----------------
// QBLK=128 (4 waves), 512 blocks, serial q-tile pair (15-pr, pr) -> 34 iters each;
// 2 blocks/CU. K rows pre-permuted -> shuffle-free P routing; in-reg P.
__global__ __launch_bounds__(256, 2) void attn128_k(const unsigned short* __restrict__ Q,
                                                    const unsigned short* __restrict__ Kg,
                                                    const unsigned short* __restrict__ Vt,
                                                    unsigned short* __restrict__ ctx) {
  __shared__ __align__(16) unsigned short Kl[2][64 * 128]; // [kv-slot][k] swizzled rows (256B)
  __shared__ __align__(16) unsigned short Vl[2][128 * 64]; // [d][kv] swizzled rows (128B)

  const int tid = threadIdx.x;
  const int w = tid >> 6, l = tid & 63;   // w: 0..3
  const int g = l >> 4, ln = l & 15;

  // XCD grouping: 512 blocks -> 64 consecutive per XCD; each bh's 8 blocks on one XCD
  const int flat = ((blockIdx.x & 7) << 6) | (blockIdx.x >> 3);
  const int bh = flat >> 3;  // 0..63
  const int pr = flat & 7;   // 0..7 -> q-tile pair (15-pr, pr)

  const char* kbase = (const char*)(Kg + (size_t)bh * T_SEQ * HD_);
  const char* vbase = (const char*)(Vt + (size_t)bh * HD_ * T_SEQ);
  const int b = bh >> 4, h = bh & 15;

#define STAGE_KV(bufi, ktile) do {                                                    \
    int kv0_ = (ktile) * 64;                                                          \
    _Pragma("unroll")                                                                 \
    for (int i_ = 0; i_ < 4; ++i_) {                                                  \
      int c_ = w * 4 + i_;                                                            \
      int kvr_ = c_ * 4 + g;                                                          \
      gload16(kbase + ((size_t)(kv0_ + kvr_) * HD_) * 2 + ((ln * 16) ^ ((kvr_ & 7) << 4)), \
              (char*)&Kl[bufi][0] + c_ * 1024);                                       \
      int d_ = c_ * 8 + (l >> 3);                                                     \
      gload16(vbase + ((size_t)d_ * T_SEQ + kv0_) * 2 + (((l & 7) * 16) ^ ((d_ & 7) << 4)), \
              (char*)&Vl[bufi][0] + c_ * 1024);                                       \
    } } while (0)

#pragma unroll 1
  for (int half = 0; half < 2; ++half) {
    const int qt = half ? pr : (15 - pr); // heavy 128-row tile first
    const int q0 = qt << 7;
    const int qw = q0 + w * 32;           // wave's first q row

    bf16x8 bq[2][4];
#pragma unroll
    for (int f = 0; f < 2; ++f)
#pragma unroll
      for (int kk = 0; kk < 4; ++kk)
        bq[f][kk] = *(const bf16x8*)(Q + ((size_t)bh * T_SEQ + qw + f * 16 + ln) * HD_ + kk * 32 + g * 8);

    f32x4 acc[2][8] = {};
    float mrun[2] = {-INFINITY, -INFINITY};
    float lrun[2] = {0.f, 0.f};

    const int nt = (qt + 1) * 2;

    STAGE_KV(0, 0);
    __syncthreads();
    int cur = 0;

#pragma unroll 1
    for (int kt = 0; kt < nt; ++kt) {
      if (kt + 1 < nt) STAGE_KV(cur ^ 1, kt + 1); // prefetch overlaps compute
      const int kv0 = kt * 64;
      if (kv0 <= qw + 31) { // causal wave-skip (barriers stay outside)
        const char* kl = (const char*)&Kl[cur][0];
        const char* vl = (const char*)&Vl[cur][0];

        // S^T[kv-slot][q] = K . Q^T
        f32x4 st[2][4] = {};
        __builtin_amdgcn_s_setprio(1);
#pragma unroll
        for (int kk = 0; kk < 4; ++kk) {
          bf16x8 ak[4];
#pragma unroll
          for (int mf = 0; mf < 4; ++mf)
            ak[mf] = *(const bf16x8*)(kl + (mf * 16 + ln) * 256 + ((kk * 64 + g * 16) ^ ((ln & 7) << 4)));
#pragma unroll
          for (int mf = 0; mf < 4; ++mf) {
            st[0][mf] = __builtin_amdgcn_mfma_f32_16x16x32_bf16(ak[mf], bq[0][kk], st[0][mf], 0, 0, 0);
            st[1][mf] = __builtin_amdgcn_mfma_f32_16x16x32_bf16(ak[mf], bq[1][kk], st[1][mf], 0, 0, 0);
          }
        }
        __builtin_amdgcn_s_setprio(0);

        // causal mask: slot (mf,g,r) holds TRUE kv = kv0 + 32(mf>>1) + 8g + 4(mf&1) + r
        if (kv0 + 63 > qw) {
#pragma unroll
          for (int f = 0; f < 2; ++f)
#pragma unroll
            for (int mf = 0; mf < 4; ++mf)
#pragma unroll
              for (int r = 0; r < 4; ++r)
                if (kv0 + 32 * (mf >> 1) + 8 * g + 4 * (mf & 1) + r > qw + f * 16 + ln)
                  st[f][mf][r] = -INFINITY;
        }

        bf16x8 ap[2][2]; // [f][ks]
#pragma unroll
        for (int f = 0; f < 2; ++f) {
          float pmax = -INFINITY;
#pragma unroll
          for (int mf = 0; mf < 4; ++mf)
#pragma unroll
            for (int r = 0; r < 4; ++r) pmax = fmaxf(pmax, st[f][mf][r]);
          pmax = fmaxf(pmax, __shfl_xor(pmax, 16));
          pmax = fmaxf(pmax, __shfl_xor(pmax, 32));
          float msub = mrun[f];
          if (__any(pmax > mrun[f] + 8.f)) { // defer-max
            msub = fmaxf(mrun[f], pmax);
            float fac = __builtin_amdgcn_exp2f(mrun[f] - msub);
            mrun[f] = msub;
            lrun[f] *= fac;
            float fr[4];
#pragma unroll
            for (int r = 0; r < 4; ++r) fr[r] = __shfl(fac, g * 4 + r);
#pragma unroll
            for (int nf = 0; nf < 8; ++nf) {
              acc[f][nf][0] *= fr[0]; acc[f][nf][1] *= fr[1];
              acc[f][nf][2] *= fr[2]; acc[f][nf][3] *= fr[3];
            }
          }
          uint32_t Aq[4][2];
          float psum = 0.f;
#pragma unroll
          for (int mf = 0; mf < 4; ++mf) {
            float p0 = __builtin_amdgcn_exp2f(st[f][mf][0] - msub);
            float p1 = __builtin_amdgcn_exp2f(st[f][mf][1] - msub);
            float p2 = __builtin_amdgcn_exp2f(st[f][mf][2] - msub);
            float p3 = __builtin_amdgcn_exp2f(st[f][mf][3] - msub);
            psum += (p0 + p1) + (p2 + p3);
            asm("v_cvt_pk_bf16_f32 %0, %1, %2" : "=v"(Aq[mf][0]) : "v"(p0), "v"(p1));
            asm("v_cvt_pk_bf16_f32 %0, %1, %2" : "=v"(Aq[mf][1]) : "v"(p2), "v"(p3));
          }
          psum += __shfl_xor(psum, 16);
          psum += __shfl_xor(psum, 32);
          lrun[f] += psum;

          // shuffle-free routing (K-row permutation): ap[ks] = {Aq[2ks], Aq[2ks+1]}
#pragma unroll
          for (int ks = 0; ks < 2; ++ks) {
            union { uint32_t u[4]; bf16x8 v; } t;
            t.u[0] = Aq[2 * ks][0];     t.u[1] = Aq[2 * ks][1];
            t.u[2] = Aq[2 * ks + 1][0]; t.u[3] = Aq[2 * ks + 1][1];
            ap[f][ks] = t.v;
          }
        }

        __builtin_amdgcn_s_setprio(1);
#pragma unroll
        for (int nf = 0; nf < 8; ++nf) {
          int d = nf * 16 + ln;
#pragma unroll
          for (int ks = 0; ks < 2; ++ks) {
            bf16x8 bv = *(const bf16x8*)(vl + d * 128 + ((ks * 64 + g * 16) ^ ((ln & 7) << 4)));
            acc[0][nf] = __builtin_amdgcn_mfma_f32_16x16x32_bf16(ap[0][ks], bv, acc[0][nf], 0, 0, 0);
            acc[1][nf] = __builtin_amdgcn_mfma_f32_16x16x32_bf16(ap[1][ks], bv, acc[1][nf], 0, 0, 0);
          }
        }
        __builtin_amdgcn_s_setprio(0);
      }
      __syncthreads();
      cur ^= 1;
    }

    // epilogue: divide by row sum, write ctx [B, T, NH*HD]
#pragma unroll
    for (int f = 0; f < 2; ++f) {
      float inv[4];
#pragma unroll
      for (int r = 0; r < 4; ++r) inv[r] = 1.f / __shfl(lrun[f], g * 4 + r);
#pragma unroll
      for (int nf = 0; nf < 8; ++nf) {
#pragma unroll
        for (int r = 0; r < 4; ++r) {
          int qrow = qw + f * 16 + g * 4 + r;
          ctx[((size_t)(b * T_SEQ + qrow)) * H_DIM + h * HD_ + nf * 16 + ln] =
              f2b(acc[f][nf][r] * inv[r]);
        }
      }
    }
  }
#undef STAGE_KV
}

// ---------------- host launch ----------------
extern "C" void kernel_launch(void* const* d_in, const int* in_sizes, int n_in,
                              void* d_out, int out_size, void* d_ws, size_t ws_size,
                              hipStream_t stream) {
  (void)in_sizes; (void)n_in; (void)out_size; (void)ws_size;
  const float* x  = (const float*)d_in[0];
  const float* qw = (const float*)d_in[1];
  const float* qb = (const float*)d_in[2];
  const float* kw = (const float*)d_in[3];
  const float* kb = (const float*)d_in[4];
  const float* vw = (const float*)d_in[5];
  const float* vb = (const float*)d_in[6];
  const float* ow = (const float*)d_in[7];
  const float* ob = (const float*)d_in[8];

  char* ws = (char*)d_ws;
  unsigned short* xb  = (unsigned short*)(ws);              // 32 MiB (x bf16; later reused as ctx)
  unsigned short* qwb = (unsigned short*)(ws + 33554432);   // 8 MiB
  unsigned short* kwb = (unsigned short*)(ws + 41943040);
  unsigned short* vwb = (unsigned short*)(ws + 50331648);
  unsigned short* owb = (unsigned short*)(ws + 58720256);
  unsigned short* Qb  = (unsigned short*)(ws + 67108864);   // 32 MiB [B,NH,T,HD]
  unsigned short* Kb  = (unsigned short*)(ws + 100663296);  // 32 MiB (row-permuted per 64)
  unsigned short* Vtb = (unsigned short*)(ws + 134217728);  // 32 MiB [B,NH,HD,T]
  unsigned short* ctxb = xb;                                // alias: x dead after V proj

  const float cscale = 0.08838834764831845f * 1.4426950408889634f; // SCALE * log2(e)

  // all f32->bf16 conversions in ONE launch (x + 4 weight matrices)
  cvt_all_k<<<2048, dim3(256), 0, stream>>>(x, qw, kw, vw, ow, xb, qwb, kwb, vwb, owb);

  // fused Q/K/V projections: one 768-block launch (one dispatch tail, not three)
  qkv_gemm_k<<<dim3(768), dim3(512), 0, stream>>>(xb, qwb, kwb, vwb, qb, kb, vb,
                                                  Qb, Kb, Vtb, cscale);

  attn128_k<<<dim3(512), dim3(256), 0, stream>>>(Qb, Kb, Vtb, ctxb);

  gemm_out_k<<<dim3(8, 32), dim3(512), 0, stream>>>(ctxb, owb, ob, (float*)d_out);
}